// Round 3
// baseline (1568.434 us; speedup 1.0000x reference)
//
#include <hip/hip_runtime.h>
#include <hip/hip_bf16.h>

// ---------------------------------------------------------------------------
// GNNRegression: 2-layer GCN (PyG GCNConv semantics) + global mean pool + linear
//   N=50000 nodes, E=800000 edges, IN=256, HID=512, OUT=1, G=64 graphs
// Key identity: A_norm(X W) == (A_norm X) W  -> aggregate FIRST (cheaper for
// layer 1: 256 feats), then GEMM with fused bias+ReLU.
// Pipeline:
//   1. deg/cnt atomics over edges; dinv = 1/sqrt(deg+1)
//   2. CSR by dst (scan + atomic fill), per-edge norm = dinv[s]*ew*dinv[d]
//   3. agg1 = A_norm X          [50000,256]   (bufB)
//   4. h1 = relu(agg1 W1 + b1)  [50000,512]   (bufA)  64x64 tiled fp32 GEMM
//   5. agg2 = A_norm h1         [50000,512]   (bufB)
//   6. h2 = relu(agg2 W2 + b2)  [50000,512]   (bufA, overwrites h1)
//   7. per-node dot with Wl, segment-mean by batch -> out[64]
// ---------------------------------------------------------------------------

#define N_NODES 50000
#define N_EDGES 800000
#define IN_CH   256
#define HID     512
#define N_GRAPHS 64

// ---------------- workspace layout (4-byte elements) ----------------
// [gsum 64][gcnt 64][deg 50000][cnt 50000][cursor 50000]  <- zeroed region
// [dinv 50000][csrptr 50001][esrc 800000][enorm 800000]
// [pad][bufA 25.6M][bufB 25.6M]
#define OFF_GSUM   0
#define OFF_GCNT   64
#define OFF_DEG    128
#define OFF_CNT    (OFF_DEG + N_NODES)
#define OFF_CURSOR (OFF_CNT + N_NODES)
#define ZERO_ELEMS (OFF_CURSOR + N_NODES)           // 150128
#define OFF_DINV   ZERO_ELEMS
#define OFF_CSRPTR (OFF_DINV + N_NODES)
#define OFF_ESRC   (OFF_CSRPTR + N_NODES + 1)
#define OFF_ENORM  (OFF_ESRC + N_EDGES)
#define OFF_BUFA   1850368                           // 16B aligned
#define OFF_BUFB   (OFF_BUFA + N_NODES * HID)

// ---------------- kernels ----------------

__global__ __launch_bounds__(256) void k_deg_cnt(const int* __restrict__ src,
                                                 const int* __restrict__ dst,
                                                 const float* __restrict__ ew,
                                                 float* __restrict__ deg,
                                                 int* __restrict__ cnt) {
    int e = blockIdx.x * blockDim.x + threadIdx.x;
    if (e >= N_EDGES) return;
    int d = dst[e];
    atomicAdd(&deg[d], ew[e]);
    atomicAdd(&cnt[d], 1);
}

__global__ __launch_bounds__(256) void k_dinv(const float* __restrict__ deg,
                                              float* __restrict__ dinv) {
    int i = blockIdx.x * blockDim.x + threadIdx.x;
    if (i >= N_NODES) return;
    dinv[i] = 1.0f / sqrtf(deg[i] + 1.0f);   // self-loop adds 1; deg>=1 always
}

// single-block hierarchical exclusive scan of cnt[0..n) -> ptr[0..n]
__global__ __launch_bounds__(1024) void k_scan(const int* __restrict__ cnt,
                                               int* __restrict__ ptr, int n) {
    __shared__ int wsum[16];
    __shared__ int carry;
    int tid = threadIdx.x, lane = tid & 63, wid = tid >> 6;
    if (tid == 0) carry = 0;
    __syncthreads();
    for (int base = 0; base < n; base += 1024) {
        int i = base + tid;
        int v = (i < n) ? cnt[i] : 0;
        int incl = v;
        #pragma unroll
        for (int off = 1; off < 64; off <<= 1) {
            int t = __shfl_up(incl, off);
            if (lane >= off) incl += t;
        }
        if (lane == 63) wsum[wid] = incl;
        __syncthreads();
        if (tid == 0) {
            int run = carry;
            #pragma unroll
            for (int k = 0; k < 16; ++k) { int t = wsum[k]; wsum[k] = run; run += t; }
            carry = run;
        }
        __syncthreads();
        if (i < n) ptr[i] = wsum[wid] + incl - v;
        __syncthreads();   // protect wsum/carry for next chunk
    }
    if (threadIdx.x == 0) ptr[n] = carry;
}

__global__ __launch_bounds__(256) void k_fill(const int* __restrict__ src,
                                              const int* __restrict__ dst,
                                              const float* __restrict__ ew,
                                              const float* __restrict__ dinv,
                                              const int* __restrict__ csrptr,
                                              int* __restrict__ cursor,
                                              int* __restrict__ esrc,
                                              float* __restrict__ enorm) {
    int e = blockIdx.x * blockDim.x + threadIdx.x;
    if (e >= N_EDGES) return;
    int s = src[e], d = dst[e];
    int pos = csrptr[d] + atomicAdd(&cursor[d], 1);
    esrc[pos] = s;
    enorm[pos] = dinv[s] * ew[e] * dinv[d];
}

// Y[i] = sum_{e in CSR(i)} norm_e * X[src_e] + dinv[i]^2 * X[i]
// one wave per node; F = 256 or 512 (float4 per lane x NV)
template <int F>
__global__ __launch_bounds__(256) void k_agg(const float* __restrict__ X,
                                             const int* __restrict__ csrptr,
                                             const int* __restrict__ esrc,
                                             const float* __restrict__ enorm,
                                             const float* __restrict__ dinv,
                                             float* __restrict__ Y) {
    constexpr int NV = F / 256;
    int wave = (blockIdx.x * blockDim.x + threadIdx.x) >> 6;
    int lane = threadIdx.x & 63;
    if (wave >= N_NODES) return;
    int i = wave;
    float w0 = dinv[i] * dinv[i];
    const float4* xr = (const float4*)&X[(size_t)i * F];
    float4 acc[NV];
    #pragma unroll
    for (int v = 0; v < NV; ++v) {
        float4 t = xr[lane + 64 * v];
        acc[v].x = w0 * t.x; acc[v].y = w0 * t.y;
        acc[v].z = w0 * t.z; acc[v].w = w0 * t.w;
    }
    int s = csrptr[i], e = csrptr[i + 1];
    for (int j = s; j < e; ++j) {
        int sr = esrc[j];
        float w = enorm[j];
        const float4* x2 = (const float4*)&X[(size_t)sr * F];
        #pragma unroll
        for (int v = 0; v < NV; ++v) {
            float4 t = x2[lane + 64 * v];
            acc[v].x += w * t.x; acc[v].y += w * t.y;
            acc[v].z += w * t.z; acc[v].w += w * t.w;
        }
    }
    float4* yr = (float4*)&Y[(size_t)i * F];
    #pragma unroll
    for (int v = 0; v < NV; ++v) yr[lane + 64 * v] = acc[v];
}

// C = relu(A[M,K] * B[K,512] + bias), 64x64 tile, BK=16, 256 thr, 4x4 microtile
template <int K>
__global__ __launch_bounds__(256) void k_gemm_bias_relu(const float* __restrict__ A,
                                                        const float* __restrict__ B,
                                                        const float* __restrict__ bias,
                                                        float* __restrict__ C, int M) {
    constexpr int N = 512;
    __shared__ float As[16][68];   // [k][row], pad 68 (272B = 17x16B, float4-aligned)
    __shared__ float Bs[16][64];   // [k][col]
    int tid = threadIdx.x;
    int tx = tid & 15, ty = tid >> 4;
    int row0 = blockIdx.x * 64;
    int col0 = blockIdx.y * 64;
    float acc[4][4] = {};
    int lr = tid >> 2;        // A-load row 0..63
    int lq = tid & 3;         // A-load k-quad
    int bkr = tid >> 4;       // B-load k row 0..15
    int bc = (tid & 15) * 4;  // B-load col

    for (int k0 = 0; k0 < K; k0 += 16) {
        int gr = row0 + lr;
        float4 av = make_float4(0.f, 0.f, 0.f, 0.f);
        if (gr < M) av = *(const float4*)&A[(size_t)gr * K + k0 + lq * 4];
        As[lq * 4 + 0][lr] = av.x;
        As[lq * 4 + 1][lr] = av.y;
        As[lq * 4 + 2][lr] = av.z;
        As[lq * 4 + 3][lr] = av.w;
        *(float4*)&Bs[bkr][bc] = *(const float4*)&B[(size_t)(k0 + bkr) * N + col0 + bc];
        __syncthreads();
        #pragma unroll
        for (int kk = 0; kk < 16; ++kk) {
            float4 a4 = *(const float4*)&As[kk][ty * 4];
            float4 b4 = *(const float4*)&Bs[kk][tx * 4];
            float av_[4] = {a4.x, a4.y, a4.z, a4.w};
            float bv_[4] = {b4.x, b4.y, b4.z, b4.w};
            #pragma unroll
            for (int i = 0; i < 4; ++i)
                #pragma unroll
                for (int j = 0; j < 4; ++j) acc[i][j] += av_[i] * bv_[j];
        }
        __syncthreads();
    }
    #pragma unroll
    for (int i = 0; i < 4; ++i) {
        int gr = row0 + ty * 4 + i;
        if (gr < M) {
            float4 o;
            o.x = fmaxf(acc[i][0] + bias[col0 + tx * 4 + 0], 0.f);
            o.y = fmaxf(acc[i][1] + bias[col0 + tx * 4 + 1], 0.f);
            o.z = fmaxf(acc[i][2] + bias[col0 + tx * 4 + 2], 0.f);
            o.w = fmaxf(acc[i][3] + bias[col0 + tx * 4 + 3], 0.f);
            *(float4*)&C[(size_t)gr * N + col0 + tx * 4] = o;
        }
    }
}

// per-node dot(h2, Wl) -> atomic segment sums per graph
__global__ __launch_bounds__(256) void k_pool(const float* __restrict__ H,
                                              const float* __restrict__ Wl,
                                              const int* __restrict__ batch,
                                              float* __restrict__ gsum,
                                              int* __restrict__ gcnt) {
    int wave = (blockIdx.x * blockDim.x + threadIdx.x) >> 6;
    int lane = threadIdx.x & 63;
    if (wave >= N_NODES) return;
    int i = wave;
    const float4* hr = (const float4*)&H[(size_t)i * HID];
    const float4* wr = (const float4*)Wl;
    float r = 0.f;
    #pragma unroll
    for (int v = 0; v < 2; ++v) {
        float4 h = hr[lane + 64 * v];
        float4 w = wr[lane + 64 * v];
        r += h.x * w.x + h.y * w.y + h.z * w.z + h.w * w.w;
    }
    #pragma unroll
    for (int off = 32; off > 0; off >>= 1) r += __shfl_down(r, off);
    if (lane == 0) {
        int b = batch[i];
        atomicAdd(&gsum[b], r);
        atomicAdd(&gcnt[b], 1);
    }
}

__global__ __launch_bounds__(64) void k_final(const float* __restrict__ gsum,
                                              const int* __restrict__ gcnt,
                                              const float* __restrict__ bl,
                                              float* __restrict__ out) {
    int g = threadIdx.x;
    out[g] = gsum[g] / fmaxf((float)gcnt[g], 1.0f) + bl[0];
}

// ---------------- launch ----------------

extern "C" void kernel_launch(void* const* d_in, const int* in_sizes, int n_in,
                              void* d_out, int out_size, void* d_ws, size_t ws_size,
                              hipStream_t stream) {
    const float* x  = (const float*)d_in[0];
    const int* ei   = (const int*)d_in[1];
    const float* ew = (const float*)d_in[2];
    const int* batch= (const int*)d_in[3];
    const float* W1 = (const float*)d_in[4];
    const float* b1 = (const float*)d_in[5];
    const float* W2 = (const float*)d_in[6];
    const float* b2 = (const float*)d_in[7];
    const float* Wl = (const float*)d_in[8];
    const float* bl = (const float*)d_in[9];
    float* out = (float*)d_out;

    const int* src = ei;
    const int* dst = ei + N_EDGES;

    float* ws = (float*)d_ws;
    float* gsum   = ws + OFF_GSUM;
    int*   gcnt   = (int*)(ws + OFF_GCNT);
    float* deg    = ws + OFF_DEG;
    int*   cnt    = (int*)(ws + OFF_CNT);
    int*   cursor = (int*)(ws + OFF_CURSOR);
    float* dinv   = ws + OFF_DINV;
    int*   csrptr = (int*)(ws + OFF_CSRPTR);
    int*   esrc   = (int*)(ws + OFF_ESRC);
    float* enorm  = ws + OFF_ENORM;
    float* bufA   = ws + OFF_BUFA;   // h1 then h2
    float* bufB   = ws + OFF_BUFB;   // agg1 then agg2

    // zero the atomic-accumulated region in one memset
    hipMemsetAsync(ws, 0, (size_t)ZERO_ELEMS * 4, stream);

    int eb = (N_EDGES + 255) / 256;
    int nb = (N_NODES + 255) / 256;
    int wb = (N_NODES * 64 + 255) / 256;   // one wave per node

    k_deg_cnt<<<eb, 256, 0, stream>>>(src, dst, ew, deg, cnt);
    k_dinv<<<nb, 256, 0, stream>>>(deg, dinv);
    k_scan<<<1, 1024, 0, stream>>>(cnt, csrptr, N_NODES);
    k_fill<<<eb, 256, 0, stream>>>(src, dst, ew, dinv, csrptr, cursor, esrc, enorm);

    // layer 1: aggregate X (256 feats) then GEMM -> h1
    k_agg<IN_CH><<<wb, 256, 0, stream>>>(x, csrptr, esrc, enorm, dinv, bufB);
    dim3 g1((N_NODES + 63) / 64, HID / 64);
    k_gemm_bias_relu<IN_CH><<<g1, 256, 0, stream>>>(bufB, W1, b1, bufA, N_NODES);

    // layer 2: aggregate h1 (512 feats) then GEMM -> h2 (overwrites h1's buffer)
    k_agg<HID><<<wb, 256, 0, stream>>>(bufA, csrptr, esrc, enorm, dinv, bufB);
    k_gemm_bias_relu<HID><<<g1, 256, 0, stream>>>(bufB, W2, b2, bufA, N_NODES);

    // pool + head
    k_pool<<<wb, 256, 0, stream>>>(bufA, Wl, batch, gsum, gcnt);
    k_final<<<1, 64, 0, stream>>>(gsum, gcnt, bl, out);
}

// Round 4
// 1244.645 us; speedup vs baseline: 1.2601x; 1.2601x over previous
//
#include <hip/hip_runtime.h>
#include <hip/hip_bf16.h>

// ---------------------------------------------------------------------------
// GNNRegression: 2-layer GCN (PyG GCNConv semantics) + global mean pool + linear
//   N=50000 nodes, E=800000 edges, IN=256, HID=512, OUT=1, G=64 graphs
// Key identity: A_norm(X W) == (A_norm X) W  -> aggregate FIRST (cheaper for
// layer 1: 256 feats), then GEMM with fused bias+ReLU.
// R3 change: k_pool's 100k device atomics onto 8 cache lines (sorted batch ->
// same-line contention) cost 414us at 1% VALU / 1.7% HBM. Replaced with
// atomic-free k_dot (per-node scalar) + k_gpool (block-per-graph reduction).
// ---------------------------------------------------------------------------

#define N_NODES 50000
#define N_EDGES 800000
#define IN_CH   256
#define HID     512
#define N_GRAPHS 64

// ---------------- workspace layout (4-byte elements) ----------------
// [gsum 64][gcnt 64][deg 50000][cnt 50000][cursor 50000]  <- zeroed region
// [dinv 50000][csrptr 50001][esrc 800000][enorm 800000]
// [pad][bufA 25.6M][bufB 25.6M]
// nodedot reuses the cursor region (cursor is dead after k_fill).
#define OFF_GSUM   0
#define OFF_GCNT   64
#define OFF_DEG    128
#define OFF_CNT    (OFF_DEG + N_NODES)
#define OFF_CURSOR (OFF_CNT + N_NODES)
#define ZERO_ELEMS (OFF_CURSOR + N_NODES)           // 150128
#define OFF_DINV   ZERO_ELEMS
#define OFF_CSRPTR (OFF_DINV + N_NODES)
#define OFF_ESRC   (OFF_CSRPTR + N_NODES + 1)
#define OFF_ENORM  (OFF_ESRC + N_EDGES)
#define OFF_BUFA   1850368                           // 16B aligned
#define OFF_BUFB   (OFF_BUFA + N_NODES * HID)

// ---------------- kernels ----------------

__global__ __launch_bounds__(256) void k_deg_cnt(const int* __restrict__ src,
                                                 const int* __restrict__ dst,
                                                 const float* __restrict__ ew,
                                                 float* __restrict__ deg,
                                                 int* __restrict__ cnt) {
    int e = blockIdx.x * blockDim.x + threadIdx.x;
    if (e >= N_EDGES) return;
    int d = dst[e];
    atomicAdd(&deg[d], ew[e]);
    atomicAdd(&cnt[d], 1);
}

__global__ __launch_bounds__(256) void k_dinv(const float* __restrict__ deg,
                                              float* __restrict__ dinv) {
    int i = blockIdx.x * blockDim.x + threadIdx.x;
    if (i >= N_NODES) return;
    dinv[i] = 1.0f / sqrtf(deg[i] + 1.0f);   // self-loop adds 1; deg>=1 always
}

// single-block hierarchical exclusive scan of cnt[0..n) -> ptr[0..n]
__global__ __launch_bounds__(1024) void k_scan(const int* __restrict__ cnt,
                                               int* __restrict__ ptr, int n) {
    __shared__ int wsum[16];
    __shared__ int carry;
    int tid = threadIdx.x, lane = tid & 63, wid = tid >> 6;
    if (tid == 0) carry = 0;
    __syncthreads();
    for (int base = 0; base < n; base += 1024) {
        int i = base + tid;
        int v = (i < n) ? cnt[i] : 0;
        int incl = v;
        #pragma unroll
        for (int off = 1; off < 64; off <<= 1) {
            int t = __shfl_up(incl, off);
            if (lane >= off) incl += t;
        }
        if (lane == 63) wsum[wid] = incl;
        __syncthreads();
        if (tid == 0) {
            int run = carry;
            #pragma unroll
            for (int k = 0; k < 16; ++k) { int t = wsum[k]; wsum[k] = run; run += t; }
            carry = run;
        }
        __syncthreads();
        if (i < n) ptr[i] = wsum[wid] + incl - v;
        __syncthreads();   // protect wsum/carry for next chunk
    }
    if (threadIdx.x == 0) ptr[n] = carry;
}

__global__ __launch_bounds__(256) void k_fill(const int* __restrict__ src,
                                              const int* __restrict__ dst,
                                              const float* __restrict__ ew,
                                              const float* __restrict__ dinv,
                                              const int* __restrict__ csrptr,
                                              int* __restrict__ cursor,
                                              int* __restrict__ esrc,
                                              float* __restrict__ enorm) {
    int e = blockIdx.x * blockDim.x + threadIdx.x;
    if (e >= N_EDGES) return;
    int s = src[e], d = dst[e];
    int pos = csrptr[d] + atomicAdd(&cursor[d], 1);
    esrc[pos] = s;
    enorm[pos] = dinv[s] * ew[e] * dinv[d];
}

// Y[i] = sum_{e in CSR(i)} norm_e * X[src_e] + dinv[i]^2 * X[i]
// one wave per node; F = 256 or 512 (float4 per lane x NV)
template <int F>
__global__ __launch_bounds__(256) void k_agg(const float* __restrict__ X,
                                             const int* __restrict__ csrptr,
                                             const int* __restrict__ esrc,
                                             const float* __restrict__ enorm,
                                             const float* __restrict__ dinv,
                                             float* __restrict__ Y) {
    constexpr int NV = F / 256;
    int wave = (blockIdx.x * blockDim.x + threadIdx.x) >> 6;
    int lane = threadIdx.x & 63;
    if (wave >= N_NODES) return;
    int i = wave;
    float w0 = dinv[i] * dinv[i];
    const float4* xr = (const float4*)&X[(size_t)i * F];
    float4 acc[NV];
    #pragma unroll
    for (int v = 0; v < NV; ++v) {
        float4 t = xr[lane + 64 * v];
        acc[v].x = w0 * t.x; acc[v].y = w0 * t.y;
        acc[v].z = w0 * t.z; acc[v].w = w0 * t.w;
    }
    int s = csrptr[i], e = csrptr[i + 1];
    for (int j = s; j < e; ++j) {
        int sr = esrc[j];
        float w = enorm[j];
        const float4* x2 = (const float4*)&X[(size_t)sr * F];
        #pragma unroll
        for (int v = 0; v < NV; ++v) {
            float4 t = x2[lane + 64 * v];
            acc[v].x += w * t.x; acc[v].y += w * t.y;
            acc[v].z += w * t.z; acc[v].w += w * t.w;
        }
    }
    float4* yr = (float4*)&Y[(size_t)i * F];
    #pragma unroll
    for (int v = 0; v < NV; ++v) yr[lane + 64 * v] = acc[v];
}

// C = relu(A[M,K] * B[K,512] + bias), 64x64 tile, BK=16, 256 thr, 4x4 microtile
template <int K>
__global__ __launch_bounds__(256) void k_gemm_bias_relu(const float* __restrict__ A,
                                                        const float* __restrict__ B,
                                                        const float* __restrict__ bias,
                                                        float* __restrict__ C, int M) {
    constexpr int N = 512;
    __shared__ float As[16][68];   // [k][row], pad 68 (272B = 17x16B, float4-aligned)
    __shared__ float Bs[16][64];   // [k][col]
    int tid = threadIdx.x;
    int tx = tid & 15, ty = tid >> 4;
    int row0 = blockIdx.x * 64;
    int col0 = blockIdx.y * 64;
    float acc[4][4] = {};
    int lr = tid >> 2;        // A-load row 0..63
    int lq = tid & 3;         // A-load k-quad
    int bkr = tid >> 4;       // B-load k row 0..15
    int bc = (tid & 15) * 4;  // B-load col

    for (int k0 = 0; k0 < K; k0 += 16) {
        int gr = row0 + lr;
        float4 av = make_float4(0.f, 0.f, 0.f, 0.f);
        if (gr < M) av = *(const float4*)&A[(size_t)gr * K + k0 + lq * 4];
        As[lq * 4 + 0][lr] = av.x;
        As[lq * 4 + 1][lr] = av.y;
        As[lq * 4 + 2][lr] = av.z;
        As[lq * 4 + 3][lr] = av.w;
        *(float4*)&Bs[bkr][bc] = *(const float4*)&B[(size_t)(k0 + bkr) * N + col0 + bc];
        __syncthreads();
        #pragma unroll
        for (int kk = 0; kk < 16; ++kk) {
            float4 a4 = *(const float4*)&As[kk][ty * 4];
            float4 b4 = *(const float4*)&Bs[kk][tx * 4];
            float av_[4] = {a4.x, a4.y, a4.z, a4.w};
            float bv_[4] = {b4.x, b4.y, b4.z, b4.w};
            #pragma unroll
            for (int i = 0; i < 4; ++i)
                #pragma unroll
                for (int j = 0; j < 4; ++j) acc[i][j] += av_[i] * bv_[j];
        }
        __syncthreads();
    }
    #pragma unroll
    for (int i = 0; i < 4; ++i) {
        int gr = row0 + ty * 4 + i;
        if (gr < M) {
            float4 o;
            o.x = fmaxf(acc[i][0] + bias[col0 + tx * 4 + 0], 0.f);
            o.y = fmaxf(acc[i][1] + bias[col0 + tx * 4 + 1], 0.f);
            o.z = fmaxf(acc[i][2] + bias[col0 + tx * 4 + 2], 0.f);
            o.w = fmaxf(acc[i][3] + bias[col0 + tx * 4 + 3], 0.f);
            *(float4*)&C[(size_t)gr * N + col0 + tx * 4] = o;
        }
    }
}

// per-node dot(h2, Wl) -> nodedot[i]  (NO atomics)
__global__ __launch_bounds__(256) void k_dot(const float* __restrict__ H,
                                             const float* __restrict__ Wl,
                                             float* __restrict__ nodedot) {
    int wave = (blockIdx.x * blockDim.x + threadIdx.x) >> 6;
    int lane = threadIdx.x & 63;
    if (wave >= N_NODES) return;
    int i = wave;
    const float4* hr = (const float4*)&H[(size_t)i * HID];
    const float4* wr = (const float4*)Wl;
    float r = 0.f;
    #pragma unroll
    for (int v = 0; v < 2; ++v) {
        float4 h = hr[lane + 64 * v];
        float4 w = wr[lane + 64 * v];
        r += h.x * w.x + h.y * w.y + h.z * w.z + h.w * w.w;
    }
    #pragma unroll
    for (int off = 32; off > 0; off >>= 1) r += __shfl_down(r, off);
    if (lane == 0) nodedot[i] = r;
}

// block-per-graph segment mean over sorted batch (NO atomics)
__global__ __launch_bounds__(256) void k_gpool(const float* __restrict__ nodedot,
                                               const int* __restrict__ batch,
                                               const float* __restrict__ bl,
                                               float* __restrict__ out) {
    int g = blockIdx.x;
    int tid = threadIdx.x;
    float s = 0.f;
    int c = 0;
    for (int i = tid; i < N_NODES; i += 256) {
        bool m = (batch[i] == g);
        s += m ? nodedot[i] : 0.f;
        c += m ? 1 : 0;
    }
    __shared__ float ss[4];
    __shared__ int sc[4];
    int lane = tid & 63, wid = tid >> 6;
    #pragma unroll
    for (int off = 32; off > 0; off >>= 1) {
        s += __shfl_down(s, off);
        c += __shfl_down(c, off);
    }
    if (lane == 0) { ss[wid] = s; sc[wid] = c; }
    __syncthreads();
    if (tid == 0) {
        float S = ss[0] + ss[1] + ss[2] + ss[3];
        int C = sc[0] + sc[1] + sc[2] + sc[3];
        out[g] = S / fmaxf((float)C, 1.0f) + bl[0];
    }
}

// ---------------- launch ----------------

extern "C" void kernel_launch(void* const* d_in, const int* in_sizes, int n_in,
                              void* d_out, int out_size, void* d_ws, size_t ws_size,
                              hipStream_t stream) {
    const float* x  = (const float*)d_in[0];
    const int* ei   = (const int*)d_in[1];
    const float* ew = (const float*)d_in[2];
    const int* batch= (const int*)d_in[3];
    const float* W1 = (const float*)d_in[4];
    const float* b1 = (const float*)d_in[5];
    const float* W2 = (const float*)d_in[6];
    const float* b2 = (const float*)d_in[7];
    const float* Wl = (const float*)d_in[8];
    const float* bl = (const float*)d_in[9];
    float* out = (float*)d_out;

    const int* src = ei;
    const int* dst = ei + N_EDGES;

    float* ws = (float*)d_ws;
    float* deg    = ws + OFF_DEG;
    int*   cnt    = (int*)(ws + OFF_CNT);
    int*   cursor = (int*)(ws + OFF_CURSOR);
    float* nodedot= ws + OFF_CURSOR;     // cursor is dead after k_fill; reuse
    float* dinv   = ws + OFF_DINV;
    int*   csrptr = (int*)(ws + OFF_CSRPTR);
    int*   esrc   = (int*)(ws + OFF_ESRC);
    float* enorm  = ws + OFF_ENORM;
    float* bufA   = ws + OFF_BUFA;   // h1 then h2
    float* bufB   = ws + OFF_BUFB;   // agg1 then agg2

    // zero the atomic-accumulated region in one memset
    hipMemsetAsync(ws, 0, (size_t)ZERO_ELEMS * 4, stream);

    int eb = (N_EDGES + 255) / 256;
    int nb = (N_NODES + 255) / 256;
    int wb = (N_NODES * 64 + 255) / 256;   // one wave per node

    k_deg_cnt<<<eb, 256, 0, stream>>>(src, dst, ew, deg, cnt);
    k_dinv<<<nb, 256, 0, stream>>>(deg, dinv);
    k_scan<<<1, 1024, 0, stream>>>(cnt, csrptr, N_NODES);
    k_fill<<<eb, 256, 0, stream>>>(src, dst, ew, dinv, csrptr, cursor, esrc, enorm);

    // layer 1: aggregate X (256 feats) then GEMM -> h1
    k_agg<IN_CH><<<wb, 256, 0, stream>>>(x, csrptr, esrc, enorm, dinv, bufB);
    dim3 g1((N_NODES + 63) / 64, HID / 64);
    k_gemm_bias_relu<IN_CH><<<g1, 256, 0, stream>>>(bufB, W1, b1, bufA, N_NODES);

    // layer 2: aggregate h1 (512 feats) then GEMM -> h2 (overwrites h1's buffer)
    k_agg<HID><<<wb, 256, 0, stream>>>(bufA, csrptr, esrc, enorm, dinv, bufB);
    k_gemm_bias_relu<HID><<<g1, 256, 0, stream>>>(bufB, W2, b2, bufA, N_NODES);

    // pool + head: atomic-free
    k_dot<<<wb, 256, 0, stream>>>(bufA, Wl, nodedot);
    k_gpool<<<N_GRAPHS, 256, 0, stream>>>(nodedot, batch, bl, out);
}

// Round 5
// 1065.755 us; speedup vs baseline: 1.4717x; 1.1679x over previous
//
#include <hip/hip_runtime.h>
#include <hip/hip_bf16.h>

// ---------------------------------------------------------------------------
// GNNRegression: 2-layer GCN + global mean pool + linear head. MI355X gfx950.
// R3: atomic-free pool (1568->1245us).
// R4: fp32 VALU GEMM (72 TF, VALUBusy 87%) -> split-bf16 MFMA GEMM:
//     a = a_hi + a_lo (bf16 each); C ~= Ah*Bh + Ah*Bl + Al*Bh (err ~2^-18).
//     Global-direct fragments (no LDS staging -> no layout/barrier risk),
//     128x128 block tile, 4 waves x 64x64, mfma_f32_16x16x32_bf16.
//     k_agg writes hi/lo bf16 directly (same bytes as old fp32 write).
//     GEMM2 epilogue fuses bias+relu+dot(Wl) -> partial rows pd[8][M'],
//     removing k_dot and the 102 MB h2 buffer.
// ---------------------------------------------------------------------------

#define N_NODES 50000
#define N_EDGES 800000
#define IN_CH   256
#define HID     512
#define N_GRAPHS 64
#define PDS     50048   // pd row stride (50000 padded to 128)

typedef short bf16x8 __attribute__((ext_vector_type(8)));
typedef float f32x4  __attribute__((ext_vector_type(4)));

// ---------------- workspace layout (4-byte slots) ----------------
#define OFF_DEG    128
#define OFF_CNT    (OFF_DEG + N_NODES)
#define OFF_CURSOR (OFF_CNT + N_NODES)
#define ZERO_ELEMS (OFF_CURSOR + N_NODES)            // 150128
#define OFF_DINV   ZERO_ELEMS
#define OFF_CSRPTR (OFF_DINV + N_NODES)
#define OFF_ESRC   (OFF_CSRPTR + N_NODES + 1)
#define OFF_ENORM  (OFF_ESRC + N_EDGES)
#define OFF_BT1H   1850368                           // 256*512 bf16 = 65536 slots
#define OFF_BT1L   (OFF_BT1H + 65536)
#define OFF_BT2H   (OFF_BT1L + 65536)                // 512*512 bf16 = 131072 slots
#define OFF_BT2L   (OFF_BT2H + 131072)
#define OFF_PD     (OFF_BT2L + 131072)               // 8*PDS floats
#define OFF_AREG   2643968                           // 25.6M slots (a1 then a2)
#define OFF_H1     (OFF_AREG + 25600000)             // 25.6M floats
// end = 53,843,968 slots = 215.4 MB

// ---------------- helpers ----------------

static __device__ inline unsigned short f2bf(float f) {   // RTN-even, no NaN here
    unsigned int u = __float_as_uint(f);
    return (unsigned short)((u + 0x7fff + ((u >> 16) & 1)) >> 16);
}
static __device__ inline float bf2f(unsigned short b) {
    return __uint_as_float(((unsigned int)b) << 16);
}
static __device__ inline void split_bf16(float v, unsigned short& hi, unsigned short& lo) {
    hi = f2bf(v);
    lo = f2bf(v - bf2f(hi));
}

// ---------------- CSR build ----------------

__global__ __launch_bounds__(256) void k_deg_cnt(const int* __restrict__ src,
                                                 const int* __restrict__ dst,
                                                 const float* __restrict__ ew,
                                                 float* __restrict__ deg,
                                                 int* __restrict__ cnt) {
    int e = blockIdx.x * blockDim.x + threadIdx.x;
    if (e >= N_EDGES) return;
    int d = dst[e];
    atomicAdd(&deg[d], ew[e]);
    atomicAdd(&cnt[d], 1);
}

__global__ __launch_bounds__(256) void k_dinv(const float* __restrict__ deg,
                                              float* __restrict__ dinv) {
    int i = blockIdx.x * blockDim.x + threadIdx.x;
    if (i >= N_NODES) return;
    dinv[i] = 1.0f / sqrtf(deg[i] + 1.0f);
}

__global__ __launch_bounds__(1024) void k_scan(const int* __restrict__ cnt,
                                               int* __restrict__ ptr, int n) {
    __shared__ int wsum[16];
    __shared__ int carry;
    int tid = threadIdx.x, lane = tid & 63, wid = tid >> 6;
    if (tid == 0) carry = 0;
    __syncthreads();
    for (int base = 0; base < n; base += 1024) {
        int i = base + tid;
        int v = (i < n) ? cnt[i] : 0;
        int incl = v;
        #pragma unroll
        for (int off = 1; off < 64; off <<= 1) {
            int t = __shfl_up(incl, off);
            if (lane >= off) incl += t;
        }
        if (lane == 63) wsum[wid] = incl;
        __syncthreads();
        if (tid == 0) {
            int run = carry;
            #pragma unroll
            for (int k = 0; k < 16; ++k) { int t = wsum[k]; wsum[k] = run; run += t; }
            carry = run;
        }
        __syncthreads();
        if (i < n) ptr[i] = wsum[wid] + incl - v;
        __syncthreads();
    }
    if (threadIdx.x == 0) ptr[n] = carry;
}

__global__ __launch_bounds__(256) void k_fill(const int* __restrict__ src,
                                              const int* __restrict__ dst,
                                              const float* __restrict__ ew,
                                              const float* __restrict__ dinv,
                                              const int* __restrict__ csrptr,
                                              int* __restrict__ cursor,
                                              int* __restrict__ esrc,
                                              float* __restrict__ enorm) {
    int e = blockIdx.x * blockDim.x + threadIdx.x;
    if (e >= N_EDGES) return;
    int s = src[e], d = dst[e];
    int pos = csrptr[d] + atomicAdd(&cursor[d], 1);
    esrc[pos] = s;
    enorm[pos] = dinv[s] * ew[e] * dinv[d];
}

// ---------------- weight transpose + split:  W[K][512] -> BT_hi/lo[512][K] ----------------

template <int K>
__global__ __launch_bounds__(256) void k_convw(const float* __restrict__ W,
                                               unsigned short* __restrict__ BTh,
                                               unsigned short* __restrict__ BTl) {
    int idx = blockIdx.x * 256 + threadIdx.x;
    if (idx >= K * 512) return;
    int k = idx >> 9, n = idx & 511;          // coalesced read of W
    unsigned short h, l;
    split_bf16(W[idx], h, l);
    BTh[(size_t)n * K + k] = h;
    BTl[(size_t)n * K + k] = l;
}

// ---------------- aggregation: Y = A_norm X, emitted as bf16 hi/lo ----------------

template <int F>
__global__ __launch_bounds__(256) void k_agg(const float* __restrict__ X,
                                             const int* __restrict__ csrptr,
                                             const int* __restrict__ esrc,
                                             const float* __restrict__ enorm,
                                             const float* __restrict__ dinv,
                                             unsigned short* __restrict__ Yh,
                                             unsigned short* __restrict__ Yl) {
    constexpr int NV = F / 256;
    int wave = (blockIdx.x * blockDim.x + threadIdx.x) >> 6;
    int lane = threadIdx.x & 63;
    if (wave >= N_NODES) return;
    int i = wave;
    float w0 = dinv[i] * dinv[i];
    const float4* xr = (const float4*)&X[(size_t)i * F];
    float4 acc[NV];
    #pragma unroll
    for (int v = 0; v < NV; ++v) {
        float4 t = xr[lane + 64 * v];
        acc[v].x = w0 * t.x; acc[v].y = w0 * t.y;
        acc[v].z = w0 * t.z; acc[v].w = w0 * t.w;
    }
    int s = csrptr[i], e = csrptr[i + 1];
    for (int j = s; j < e; ++j) {
        int sr = esrc[j];
        float w = enorm[j];
        const float4* x2 = (const float4*)&X[(size_t)sr * F];
        #pragma unroll
        for (int v = 0; v < NV; ++v) {
            float4 t = x2[lane + 64 * v];
            acc[v].x += w * t.x; acc[v].y += w * t.y;
            acc[v].z += w * t.z; acc[v].w += w * t.w;
        }
    }
    #pragma unroll
    for (int v = 0; v < NV; ++v) {
        size_t base = (size_t)i * F + (size_t)(lane + 64 * v) * 4;
        ushort4 hv, lv;
        split_bf16(acc[v].x, hv.x, lv.x);
        split_bf16(acc[v].y, hv.y, lv.y);
        split_bf16(acc[v].z, hv.z, lv.z);
        split_bf16(acc[v].w, hv.w, lv.w);
        *(ushort4*)&Yh[base] = hv;
        *(ushort4*)&Yl[base] = lv;
    }
}

// ---------------- split-bf16 MFMA GEMM ----------------
// C[M,512] = relu(A * B + bias); A as hi/lo bf16 [M][K], B as hi/lo bf16 B^T [512][K].
// Block: 128 rows x 128 cols, 4 waves (2x2), wave = 64x64 = 4x4 MFMA frags.
// Fragment layouts (guide-verified): A/B lane l holds 8 contiguous k at
// row/col = l&15, k0 = (l>>4)*8.  C/D: col = l&15, row = (l>>4)*4 + reg.
// DOT=false: store C fp32. DOT=true: fuse dot(relu(..), Wl) -> pd[colblk*2+wn][row].
template <int K, bool DOT>
__global__ __launch_bounds__(256) void k_mgemm(const unsigned short* __restrict__ Ah,
                                               const unsigned short* __restrict__ Al,
                                               const unsigned short* __restrict__ BTh,
                                               const unsigned short* __restrict__ BTl,
                                               const float* __restrict__ bias,
                                               float* __restrict__ C,
                                               const float* __restrict__ Wl,
                                               float* __restrict__ pd) {
    int tid = threadIdx.x, lane = tid & 63, wid = tid >> 6;
    int wm = wid >> 1, wn = wid & 1;
    int colblk = blockIdx.x;                          // col in x: A-panel sharers adjacent
    int row0 = blockIdx.y * 128 + wm * 64;
    int col0 = colblk * 128 + wn * 64;
    int l15 = lane & 15, l4 = lane >> 4;

    f32x4 acc[4][4];
    #pragma unroll
    for (int a = 0; a < 4; ++a)
        #pragma unroll
        for (int b = 0; b < 4; ++b) acc[a][b] = (f32x4){0.f, 0.f, 0.f, 0.f};

    for (int k0 = 0; k0 < K; k0 += 32) {
        int ka = k0 + l4 * 8;
        bf16x8 ah[4], al[4], bh[4], bl[4];
        #pragma unroll
        for (int mf = 0; mf < 4; ++mf) {
            int r = row0 + mf * 16 + l15;
            if (r >= N_NODES) r = N_NODES - 1;        // clamped read, discarded on store
            ah[mf] = *(const bf16x8*)&Ah[(size_t)r * K + ka];
            al[mf] = *(const bf16x8*)&Al[(size_t)r * K + ka];
        }
        #pragma unroll
        for (int nf = 0; nf < 4; ++nf) {
            int c = col0 + nf * 16 + l15;
            bh[nf] = *(const bf16x8*)&BTh[(size_t)c * K + ka];
            bl[nf] = *(const bf16x8*)&BTl[(size_t)c * K + ka];
        }
        #pragma unroll
        for (int mf = 0; mf < 4; ++mf)
            #pragma unroll
            for (int nf = 0; nf < 4; ++nf) {
                acc[mf][nf] = __builtin_amdgcn_mfma_f32_16x16x32_bf16(ah[mf], bh[nf], acc[mf][nf], 0, 0, 0);
                acc[mf][nf] = __builtin_amdgcn_mfma_f32_16x16x32_bf16(ah[mf], bl[nf], acc[mf][nf], 0, 0, 0);
                acc[mf][nf] = __builtin_amdgcn_mfma_f32_16x16x32_bf16(al[mf], bh[nf], acc[mf][nf], 0, 0, 0);
            }
    }

    if (!DOT) {
        #pragma unroll
        for (int mf = 0; mf < 4; ++mf)
            #pragma unroll
            for (int nf = 0; nf < 4; ++nf) {
                int c = col0 + nf * 16 + l15;
                float bv = bias[c];
                #pragma unroll
                for (int r = 0; r < 4; ++r) {
                    int row = row0 + mf * 16 + l4 * 4 + r;
                    if (row < N_NODES)
                        C[(size_t)row * 512 + c] = fmaxf(acc[mf][nf][r] + bv, 0.f);
                }
            }
    } else {
        float rowsum[4][4];
        #pragma unroll
        for (int mf = 0; mf < 4; ++mf)
            #pragma unroll
            for (int r = 0; r < 4; ++r) rowsum[mf][r] = 0.f;
        #pragma unroll
        for (int nf = 0; nf < 4; ++nf) {
            int c = col0 + nf * 16 + l15;
            float bv = bias[c];
            float wv = Wl[c];
            #pragma unroll
            for (int mf = 0; mf < 4; ++mf)
                #pragma unroll
                for (int r = 0; r < 4; ++r)
                    rowsum[mf][r] += fmaxf(acc[mf][nf][r] + bv, 0.f) * wv;
        }
        // reduce across the 16 lanes (same l4 group) holding different cols
        #pragma unroll
        for (int mf = 0; mf < 4; ++mf)
            #pragma unroll
            for (int r = 0; r < 4; ++r) {
                float v = rowsum[mf][r];
                #pragma unroll
                for (int mask = 1; mask <= 8; mask <<= 1) v += __shfl_xor(v, mask);
                if (l15 == 0) {
                    int row = row0 + mf * 16 + l4 * 4 + r;
                    if (row < N_NODES)
                        pd[(size_t)(colblk * 2 + wn) * PDS + row] = v;
                }
            }
    }
}

// ---------------- pool: out[g] = mean_i(pd-sum) + bl ----------------

__global__ __launch_bounds__(256) void k_gpool(const float* __restrict__ pd,
                                               const int* __restrict__ batch,
                                               const float* __restrict__ bl,
                                               float* __restrict__ out) {
    int g = blockIdx.x;
    int tid = threadIdx.x;
    float s = 0.f;
    int c = 0;
    for (int i = tid; i < N_NODES; i += 256) {
        if (batch[i] == g) {
            float v = 0.f;
            #pragma unroll
            for (int p = 0; p < 8; ++p) v += pd[(size_t)p * PDS + i];
            s += v;
            c += 1;
        }
    }
    __shared__ float ss[4];
    __shared__ int sc[4];
    int lane = tid & 63, wid = tid >> 6;
    #pragma unroll
    for (int off = 32; off > 0; off >>= 1) {
        s += __shfl_down(s, off);
        c += __shfl_down(c, off);
    }
    if (lane == 0) { ss[wid] = s; sc[wid] = c; }
    __syncthreads();
    if (tid == 0) {
        float S = ss[0] + ss[1] + ss[2] + ss[3];
        int C = sc[0] + sc[1] + sc[2] + sc[3];
        out[g] = S / fmaxf((float)C, 1.0f) + bl[0];
    }
}

// ---------------- launch ----------------

extern "C" void kernel_launch(void* const* d_in, const int* in_sizes, int n_in,
                              void* d_out, int out_size, void* d_ws, size_t ws_size,
                              hipStream_t stream) {
    const float* x  = (const float*)d_in[0];
    const int* ei   = (const int*)d_in[1];
    const float* ew = (const float*)d_in[2];
    const int* batch= (const int*)d_in[3];
    const float* W1 = (const float*)d_in[4];
    const float* b1 = (const float*)d_in[5];
    const float* W2 = (const float*)d_in[6];
    const float* b2 = (const float*)d_in[7];
    const float* Wl = (const float*)d_in[8];
    const float* bl = (const float*)d_in[9];
    float* out = (float*)d_out;

    const int* src = ei;
    const int* dst = ei + N_EDGES;

    float* ws = (float*)d_ws;
    float* deg    = ws + OFF_DEG;
    int*   cnt    = (int*)(ws + OFF_CNT);
    int*   cursor = (int*)(ws + OFF_CURSOR);
    float* dinv   = ws + OFF_DINV;
    int*   csrptr = (int*)(ws + OFF_CSRPTR);
    int*   esrc   = (int*)(ws + OFF_ESRC);
    float* enorm  = ws + OFF_ENORM;
    unsigned short* bt1h = (unsigned short*)(ws + OFF_BT1H);
    unsigned short* bt1l = (unsigned short*)(ws + OFF_BT1L);
    unsigned short* bt2h = (unsigned short*)(ws + OFF_BT2H);
    unsigned short* bt2l = (unsigned short*)(ws + OFF_BT2L);
    float* pd     = ws + OFF_PD;
    unsigned short* a1h = (unsigned short*)(ws + OFF_AREG);              // [M,256]
    unsigned short* a1l = (unsigned short*)(ws + OFF_AREG + 6400000);
    unsigned short* a2h = (unsigned short*)(ws + OFF_AREG);              // [M,512] (a1 dead)
    unsigned short* a2l = (unsigned short*)(ws + OFF_AREG + 12800000);
    float* h1     = ws + OFF_H1;

    hipMemsetAsync(ws, 0, (size_t)ZERO_ELEMS * 4, stream);

    int eb = (N_EDGES + 255) / 256;
    int nb = (N_NODES + 255) / 256;
    int wb = (N_NODES * 64 + 255) / 256;

    k_deg_cnt<<<eb, 256, 0, stream>>>(src, dst, ew, deg, cnt);
    k_dinv<<<nb, 256, 0, stream>>>(deg, dinv);
    k_scan<<<1, 1024, 0, stream>>>(cnt, csrptr, N_NODES);
    k_fill<<<eb, 256, 0, stream>>>(src, dst, ew, dinv, csrptr, cursor, esrc, enorm);

    k_convw<IN_CH><<<(IN_CH * 512 + 255) / 256, 256, 0, stream>>>(W1, bt1h, bt1l);
    k_convw<HID><<<(HID * 512 + 255) / 256, 256, 0, stream>>>(W2, bt2h, bt2l);

    dim3 gg(4, (N_NODES + 127) / 128);   // x = col-block (A-panel sharers adjacent)

    // layer 1
    k_agg<IN_CH><<<wb, 256, 0, stream>>>(x, csrptr, esrc, enorm, dinv, a1h, a1l);
    k_mgemm<IN_CH, false><<<gg, 256, 0, stream>>>(a1h, a1l, bt1h, bt1l, b1, h1, nullptr, nullptr);

    // layer 2 (+ fused dot with Wl)
    k_agg<HID><<<wb, 256, 0, stream>>>(h1, csrptr, esrc, enorm, dinv, a2h, a2l);
    k_mgemm<HID, true><<<gg, 256, 0, stream>>>(a2h, a2l, bt2h, bt2l, b2, nullptr, Wl, pd);

    // pool + head
    k_gpool<<<N_GRAPHS, 256, 0, stream>>>(pd, batch, bl, out);
}

// Round 6
// 936.666 us; speedup vs baseline: 1.6745x; 1.1378x over previous
//
#include <hip/hip_runtime.h>
#include <hip/hip_bf16.h>

// ---------------------------------------------------------------------------
// GNNRegression: 2-layer GCN + global mean pool + linear head. MI355X gfx950.
// R3: atomic-free pool (1568->1245us).
// R4: split-bf16 MFMA GEMM, fused dot epilogue (1245->1066us).
// R5: k_agg<512> top (256us, FETCH 826MB, HBM 46%): gather is traffic-bound.
//     (a) gather operands stored bf16 (x pre-quantized; h1 written bf16 by
//         mgemm1 epilogue) -> gather bytes & load-count halve. Accumulation
//         stays fp32; GEMM A/B keep hi/lo split (only gather inputs quantized).
//     (b) mgemm XCD swizzle: col-siblings sharing an A-panel placed 8 apart
//         in dispatch order (same XCD under round-robin) -> A-fetch /4.
// ---------------------------------------------------------------------------

#define N_NODES 50000
#define N_EDGES 800000
#define IN_CH   256
#define HID     512
#define N_GRAPHS 64
#define PDS     50048   // pd row stride (50000 padded to 128)
#define NRB     391     // row blocks of 128
#define MG_GRID 1568    // ceil(NRB,8)=392 rowblks * 4 colblks

typedef short bf16x8 __attribute__((ext_vector_type(8)));
typedef float f32x4  __attribute__((ext_vector_type(4)));

// ---------------- workspace layout (4-byte slots) ----------------
#define OFF_DEG    128
#define OFF_CNT    (OFF_DEG + N_NODES)
#define OFF_CURSOR (OFF_CNT + N_NODES)
#define ZERO_ELEMS (OFF_CURSOR + N_NODES)            // 150128
#define OFF_DINV   ZERO_ELEMS
#define OFF_CSRPTR (OFF_DINV + N_NODES)
#define OFF_ESRC   (OFF_CSRPTR + N_NODES + 1)
#define OFF_ENORM  (OFF_ESRC + N_EDGES)
#define OFF_BT1H   1850368                           // 256*512 bf16 = 65536 slots
#define OFF_BT1L   (OFF_BT1H + 65536)
#define OFF_BT2H   (OFF_BT1L + 65536)                // 512*512 bf16 = 131072 slots
#define OFF_BT2L   (OFF_BT2H + 131072)
#define OFF_PD     (OFF_BT2L + 131072)               // 8*PDS floats
#define OFF_XB     2643968                           // x bf16: 12.8M ushort = 6.4M slots
#define OFF_A1H    (OFF_XB + 6400000)                // [M,256] bf16 hi
#define OFF_A1L    (OFF_A1H + 6400000)               // [M,256] bf16 lo
#define OFF_A2H    OFF_A1H                           // [M,512] bf16 hi (a1 dead), 12.8M slots
#define OFF_A2L    (OFF_A1H + 12800000)              // [M,512] bf16 lo
#define OFF_H1B    (OFF_A2L + 12800000)              // h1 bf16 [M,512], 12.8M slots
// end = 47,443,968 slots = 189.8 MB (prior rounds used 215 MB OK)

// ---------------- helpers ----------------

static __device__ inline unsigned short f2bf(float f) {   // RTN-even
    unsigned int u = __float_as_uint(f);
    return (unsigned short)((u + 0x7fff + ((u >> 16) & 1)) >> 16);
}
static __device__ inline float bf2f(unsigned short b) {
    return __uint_as_float(((unsigned int)b) << 16);
}
static __device__ inline void split_bf16(float v, unsigned short& hi, unsigned short& lo) {
    hi = f2bf(v);
    lo = f2bf(v - bf2f(hi));
}
static __device__ inline float bflo(unsigned int u) { return __uint_as_float(u << 16); }
static __device__ inline float bfhi(unsigned int u) { return __uint_as_float(u & 0xFFFF0000u); }

// ---------------- CSR build ----------------

__global__ __launch_bounds__(256) void k_deg_cnt(const int* __restrict__ src,
                                                 const int* __restrict__ dst,
                                                 const float* __restrict__ ew,
                                                 float* __restrict__ deg,
                                                 int* __restrict__ cnt) {
    int e = blockIdx.x * blockDim.x + threadIdx.x;
    if (e >= N_EDGES) return;
    int d = dst[e];
    atomicAdd(&deg[d], ew[e]);
    atomicAdd(&cnt[d], 1);
}

__global__ __launch_bounds__(256) void k_dinv(const float* __restrict__ deg,
                                              float* __restrict__ dinv) {
    int i = blockIdx.x * blockDim.x + threadIdx.x;
    if (i >= N_NODES) return;
    dinv[i] = 1.0f / sqrtf(deg[i] + 1.0f);
}

__global__ __launch_bounds__(1024) void k_scan(const int* __restrict__ cnt,
                                               int* __restrict__ ptr, int n) {
    __shared__ int wsum[16];
    __shared__ int carry;
    int tid = threadIdx.x, lane = tid & 63, wid = tid >> 6;
    if (tid == 0) carry = 0;
    __syncthreads();
    for (int base = 0; base < n; base += 1024) {
        int i = base + tid;
        int v = (i < n) ? cnt[i] : 0;
        int incl = v;
        #pragma unroll
        for (int off = 1; off < 64; off <<= 1) {
            int t = __shfl_up(incl, off);
            if (lane >= off) incl += t;
        }
        if (lane == 63) wsum[wid] = incl;
        __syncthreads();
        if (tid == 0) {
            int run = carry;
            #pragma unroll
            for (int k = 0; k < 16; ++k) { int t = wsum[k]; wsum[k] = run; run += t; }
            carry = run;
        }
        __syncthreads();
        if (i < n) ptr[i] = wsum[wid] + incl - v;
        __syncthreads();
    }
    if (threadIdx.x == 0) ptr[n] = carry;
}

__global__ __launch_bounds__(256) void k_fill(const int* __restrict__ src,
                                              const int* __restrict__ dst,
                                              const float* __restrict__ ew,
                                              const float* __restrict__ dinv,
                                              const int* __restrict__ csrptr,
                                              int* __restrict__ cursor,
                                              int* __restrict__ esrc,
                                              float* __restrict__ enorm) {
    int e = blockIdx.x * blockDim.x + threadIdx.x;
    if (e >= N_EDGES) return;
    int s = src[e], d = dst[e];
    int pos = csrptr[d] + atomicAdd(&cursor[d], 1);
    esrc[pos] = s;
    enorm[pos] = dinv[s] * ew[e] * dinv[d];
}

// ---------------- converts ----------------

// W[K][512] fp32 -> BT_hi/lo[512][K] bf16 (full split precision kept on B)
template <int K>
__global__ __launch_bounds__(256) void k_convw(const float* __restrict__ W,
                                               unsigned short* __restrict__ BTh,
                                               unsigned short* __restrict__ BTl) {
    int idx = blockIdx.x * 256 + threadIdx.x;
    if (idx >= K * 512) return;
    int k = idx >> 9, n = idx & 511;
    unsigned short h, l;
    split_bf16(W[idx], h, l);
    BTh[(size_t)n * K + k] = h;
    BTl[(size_t)n * K + k] = l;
}

// x fp32 -> bf16 (RTN), 4 elems/thread
__global__ __launch_bounds__(256) void k_convx(const float* __restrict__ X,
                                               unsigned short* __restrict__ Xb, int n4) {
    int idx = blockIdx.x * 256 + threadIdx.x;
    if (idx >= n4) return;
    float4 v = ((const float4*)X)[idx];
    uint2 p;
    p.x = (unsigned int)f2bf(v.x) | ((unsigned int)f2bf(v.y) << 16);
    p.y = (unsigned int)f2bf(v.z) | ((unsigned int)f2bf(v.w) << 16);
    ((uint2*)Xb)[idx] = p;
}

// ---------------- aggregation: Y = A_norm X (X bf16), out hi/lo bf16 ----------------
// one wave per node; C = F/64 bf16 per lane (4 or 8)

template <int F>
__global__ __launch_bounds__(256) void k_agg(const unsigned short* __restrict__ X,
                                             const int* __restrict__ csrptr,
                                             const int* __restrict__ esrc,
                                             const float* __restrict__ enorm,
                                             const float* __restrict__ dinv,
                                             unsigned short* __restrict__ Yh,
                                             unsigned short* __restrict__ Yl) {
    constexpr int C = F / 64;            // bf16 per lane
    constexpr int U = C / 2;             // packed uints per lane
    int wave = (blockIdx.x * blockDim.x + threadIdx.x) >> 6;
    int lane = threadIdx.x & 63;
    if (wave >= N_NODES) return;
    int i = wave;
    float w0 = dinv[i] * dinv[i];
    float acc[C];
    {
        unsigned int u[U];
        const unsigned short* p = &X[(size_t)i * F + lane * C];
        if constexpr (U == 4) *(uint4*)u = *(const uint4*)p;
        else                  *(uint2*)u = *(const uint2*)p;
        #pragma unroll
        for (int j = 0; j < U; ++j) {
            acc[2 * j]     = w0 * bflo(u[j]);
            acc[2 * j + 1] = w0 * bfhi(u[j]);
        }
    }
    int s = csrptr[i], e = csrptr[i + 1];
    for (int j = s; j < e; ++j) {
        int sr = esrc[j];
        float w = enorm[j];
        unsigned int u[U];
        const unsigned short* p = &X[(size_t)sr * F + lane * C];
        if constexpr (U == 4) *(uint4*)u = *(const uint4*)p;
        else                  *(uint2*)u = *(const uint2*)p;
        #pragma unroll
        for (int q = 0; q < U; ++q) {
            acc[2 * q]     += w * bflo(u[q]);
            acc[2 * q + 1] += w * bfhi(u[q]);
        }
    }
    unsigned int ph[U], pl[U];
    #pragma unroll
    for (int j = 0; j < U; ++j) {
        unsigned short h0, l0, h1, l1;
        split_bf16(acc[2 * j], h0, l0);
        split_bf16(acc[2 * j + 1], h1, l1);
        ph[j] = (unsigned int)h0 | ((unsigned int)h1 << 16);
        pl[j] = (unsigned int)l0 | ((unsigned int)l1 << 16);
    }
    size_t base = (size_t)i * F + lane * C;
    if constexpr (U == 4) {
        *(uint4*)&Yh[base] = *(uint4*)ph;
        *(uint4*)&Yl[base] = *(uint4*)pl;
    } else {
        *(uint2*)&Yh[base] = *(uint2*)ph;
        *(uint2*)&Yl[base] = *(uint2*)pl;
    }
}

// ---------------- split-bf16 MFMA GEMM ----------------
// C[M,512] = relu(A*B + bias); A hi/lo bf16 [M][K], B hi/lo bf16 B^T [512][K].
// 1D grid, XCD swizzle: rowblk=(wgid>>5)*8+(wgid&7), colblk=(wgid>>3)&3 ->
// the 4 col-siblings of a row-panel are 8 apart (same XCD round-robin).
// DOT=false: store h1 bf16. DOT=true: fuse bias+relu+dot(Wl) -> pd.
template <int K, bool DOT>
__global__ __launch_bounds__(256) void k_mgemm(const unsigned short* __restrict__ Ah,
                                               const unsigned short* __restrict__ Al,
                                               const unsigned short* __restrict__ BTh,
                                               const unsigned short* __restrict__ BTl,
                                               const float* __restrict__ bias,
                                               unsigned short* __restrict__ Cb,
                                               const float* __restrict__ Wl,
                                               float* __restrict__ pd) {
    int wgid = blockIdx.x;
    int rowblk = (wgid >> 5) * 8 + (wgid & 7);
    if (rowblk >= NRB) return;
    int colblk = (wgid >> 3) & 3;
    int tid = threadIdx.x, lane = tid & 63, wid = tid >> 6;
    int wm = wid >> 1, wn = wid & 1;
    int row0 = rowblk * 128 + wm * 64;
    int col0 = colblk * 128 + wn * 64;
    int l15 = lane & 15, l4 = lane >> 4;

    f32x4 acc[4][4];
    #pragma unroll
    for (int a = 0; a < 4; ++a)
        #pragma unroll
        for (int b = 0; b < 4; ++b) acc[a][b] = (f32x4){0.f, 0.f, 0.f, 0.f};

    for (int k0 = 0; k0 < K; k0 += 32) {
        int ka = k0 + l4 * 8;
        bf16x8 ah[4], al[4], bh[4], bl[4];
        #pragma unroll
        for (int mf = 0; mf < 4; ++mf) {
            int r = row0 + mf * 16 + l15;
            if (r >= N_NODES) r = N_NODES - 1;        // clamped read, discarded on store
            ah[mf] = *(const bf16x8*)&Ah[(size_t)r * K + ka];
            al[mf] = *(const bf16x8*)&Al[(size_t)r * K + ka];
        }
        #pragma unroll
        for (int nf = 0; nf < 4; ++nf) {
            int c = col0 + nf * 16 + l15;
            bh[nf] = *(const bf16x8*)&BTh[(size_t)c * K + ka];
            bl[nf] = *(const bf16x8*)&BTl[(size_t)c * K + ka];
        }
        #pragma unroll
        for (int mf = 0; mf < 4; ++mf)
            #pragma unroll
            for (int nf = 0; nf < 4; ++nf) {
                acc[mf][nf] = __builtin_amdgcn_mfma_f32_16x16x32_bf16(ah[mf], bh[nf], acc[mf][nf], 0, 0, 0);
                acc[mf][nf] = __builtin_amdgcn_mfma_f32_16x16x32_bf16(ah[mf], bl[nf], acc[mf][nf], 0, 0, 0);
                acc[mf][nf] = __builtin_amdgcn_mfma_f32_16x16x32_bf16(al[mf], bh[nf], acc[mf][nf], 0, 0, 0);
            }
    }

    if (!DOT) {
        #pragma unroll
        for (int mf = 0; mf < 4; ++mf)
            #pragma unroll
            for (int nf = 0; nf < 4; ++nf) {
                int c = col0 + nf * 16 + l15;
                float bv = bias[c];
                #pragma unroll
                for (int r = 0; r < 4; ++r) {
                    int row = row0 + mf * 16 + l4 * 4 + r;
                    if (row < N_NODES)
                        Cb[(size_t)row * 512 + c] = f2bf(fmaxf(acc[mf][nf][r] + bv, 0.f));
                }
            }
    } else {
        float rowsum[4][4];
        #pragma unroll
        for (int mf = 0; mf < 4; ++mf)
            #pragma unroll
            for (int r = 0; r < 4; ++r) rowsum[mf][r] = 0.f;
        #pragma unroll
        for (int nf = 0; nf < 4; ++nf) {
            int c = col0 + nf * 16 + l15;
            float bv = bias[c];
            float wv = Wl[c];
            #pragma unroll
            for (int mf = 0; mf < 4; ++mf)
                #pragma unroll
                for (int r = 0; r < 4; ++r)
                    rowsum[mf][r] += fmaxf(acc[mf][nf][r] + bv, 0.f) * wv;
        }
        #pragma unroll
        for (int mf = 0; mf < 4; ++mf)
            #pragma unroll
            for (int r = 0; r < 4; ++r) {
                float v = rowsum[mf][r];
                #pragma unroll
                for (int mask = 1; mask <= 8; mask <<= 1) v += __shfl_xor(v, mask);
                if (l15 == 0) {
                    int row = row0 + mf * 16 + l4 * 4 + r;
                    if (row < N_NODES)
                        pd[(size_t)(colblk * 2 + wn) * PDS + row] = v;
                }
            }
    }
}

// ---------------- pool ----------------

__global__ __launch_bounds__(256) void k_gpool(const float* __restrict__ pd,
                                               const int* __restrict__ batch,
                                               const float* __restrict__ bl,
                                               float* __restrict__ out) {
    int g = blockIdx.x;
    int tid = threadIdx.x;
    float s = 0.f;
    int c = 0;
    for (int i = tid; i < N_NODES; i += 256) {
        if (batch[i] == g) {
            float v = 0.f;
            #pragma unroll
            for (int p = 0; p < 8; ++p) v += pd[(size_t)p * PDS + i];
            s += v;
            c += 1;
        }
    }
    __shared__ float ss[4];
    __shared__ int sc[4];
    int lane = tid & 63, wid = tid >> 6;
    #pragma unroll
    for (int off = 32; off > 0; off >>= 1) {
        s += __shfl_down(s, off);
        c += __shfl_down(c, off);
    }
    if (lane == 0) { ss[wid] = s; sc[wid] = c; }
    __syncthreads();
    if (tid == 0) {
        float S = ss[0] + ss[1] + ss[2] + ss[3];
        int C = sc[0] + sc[1] + sc[2] + sc[3];
        out[g] = S / fmaxf((float)C, 1.0f) + bl[0];
    }
}

// ---------------- launch ----------------

extern "C" void kernel_launch(void* const* d_in, const int* in_sizes, int n_in,
                              void* d_out, int out_size, void* d_ws, size_t ws_size,
                              hipStream_t stream) {
    const float* x  = (const float*)d_in[0];
    const int* ei   = (const int*)d_in[1];
    const float* ew = (const float*)d_in[2];
    const int* batch= (const int*)d_in[3];
    const float* W1 = (const float*)d_in[4];
    const float* b1 = (const float*)d_in[5];
    const float* W2 = (const float*)d_in[6];
    const float* b2 = (const float*)d_in[7];
    const float* Wl = (const float*)d_in[8];
    const float* bl = (const float*)d_in[9];
    float* out = (float*)d_out;

    const int* src = ei;
    const int* dst = ei + N_EDGES;

    float* ws = (float*)d_ws;
    float* deg    = ws + OFF_DEG;
    int*   cnt    = (int*)(ws + OFF_CNT);
    int*   cursor = (int*)(ws + OFF_CURSOR);
    float* dinv   = ws + OFF_DINV;
    int*   csrptr = (int*)(ws + OFF_CSRPTR);
    int*   esrc   = (int*)(ws + OFF_ESRC);
    float* enorm  = ws + OFF_ENORM;
    unsigned short* bt1h = (unsigned short*)(ws + OFF_BT1H);
    unsigned short* bt1l = (unsigned short*)(ws + OFF_BT1L);
    unsigned short* bt2h = (unsigned short*)(ws + OFF_BT2H);
    unsigned short* bt2l = (unsigned short*)(ws + OFF_BT2L);
    float* pd     = ws + OFF_PD;
    unsigned short* xb  = (unsigned short*)(ws + OFF_XB);
    unsigned short* a1h = (unsigned short*)(ws + OFF_A1H);
    unsigned short* a1l = (unsigned short*)(ws + OFF_A1L);
    unsigned short* a2h = (unsigned short*)(ws + OFF_A2H);
    unsigned short* a2l = (unsigned short*)(ws + OFF_A2L);
    unsigned short* h1b = (unsigned short*)(ws + OFF_H1B);

    hipMemsetAsync(ws, 0, (size_t)ZERO_ELEMS * 4, stream);

    int eb = (N_EDGES + 255) / 256;
    int nb = (N_NODES + 255) / 256;
    int wb = (N_NODES * 64 + 255) / 256;

    k_deg_cnt<<<eb, 256, 0, stream>>>(src, dst, ew, deg, cnt);
    k_dinv<<<nb, 256, 0, stream>>>(deg, dinv);
    k_scan<<<1, 1024, 0, stream>>>(cnt, csrptr, N_NODES);
    k_fill<<<eb, 256, 0, stream>>>(src, dst, ew, dinv, csrptr, cursor, esrc, enorm);

    k_convw<IN_CH><<<(IN_CH * 512 + 255) / 256, 256, 0, stream>>>(W1, bt1h, bt1l);
    k_convw<HID><<<(HID * 512 + 255) / 256, 256, 0, stream>>>(W2, bt2h, bt2l);
    k_convx<<<(N_NODES * IN_CH / 4 + 255) / 256, 256, 0, stream>>>(x, xb, N_NODES * IN_CH / 4);

    // layer 1
    k_agg<IN_CH><<<wb, 256, 0, stream>>>(xb, csrptr, esrc, enorm, dinv, a1h, a1l);
    k_mgemm<IN_CH, false><<<MG_GRID, 256, 0, stream>>>(a1h, a1l, bt1h, bt1l, b1, h1b, nullptr, nullptr);

    // layer 2 (+ fused dot with Wl)
    k_agg<HID><<<wb, 256, 0, stream>>>(h1b, csrptr, esrc, enorm, dinv, a2h, a2l);
    k_mgemm<HID, true><<<MG_GRID, 256, 0, stream>>>(a2h, a2l, bt2h, bt2l, b2, nullptr, Wl, pd);

    // pool + head
    k_gpool<<<N_GRAPHS, 256, 0, stream>>>(pd, batch, bl, out);
}

// Round 9
// 919.632 us; speedup vs baseline: 1.7055x; 1.0185x over previous
//
#include <hip/hip_runtime.h>
#include <hip/hip_bf16.h>

// ---------------------------------------------------------------------------
// GNNRegression: 2-layer GCN + global mean pool + linear head. MI355X gfx950.
// R3: atomic-free pool (1568->1245us).
// R4: split-bf16 MFMA GEMM, fused dot epilogue (1245->1066us).
// R5: bf16 gather operands + XCD swizzle (1066->937us).
// R6: mgemm was latency-bound (MfmaUtil 13.6%, VALU 10.6%, HBM 3.3%, occ 20%
//     -> nothing busy). Global-direct fragments replaced with the proven
//     m97/T3-minimal structure: 128x128 tile, BK=32, double-buffered LDS
//     (Ah/Al/Bh/Bl, 64KB), global_load_lds width=16 staging, 2-phase loop
//     {STAGE(next); ds_read+MFMA; __syncthreads}. LDS layout [g][row][16B]
//     gives conflict-free ds_read_b128 (full 32-bank coverage per read).
// ---------------------------------------------------------------------------

#define N_NODES 50000
#define N_EDGES 800000
#define IN_CH   256
#define HID     512
#define N_GRAPHS 64
#define PDS     50048   // pd row stride
#define NRB     391     // row blocks of 128
#define MG_GRID 1568    // 392 rowblk-slots * 4 colblks (4 tail blocks early-exit)

typedef short bf16x8 __attribute__((ext_vector_type(8)));
typedef float f32x4  __attribute__((ext_vector_type(4)));

typedef const __attribute__((address_space(1))) void* gas_ptr;
typedef __attribute__((address_space(3))) void* las_ptr;

// ---------------- workspace layout (4-byte slots) ----------------
#define OFF_DEG    128
#define OFF_CNT    (OFF_DEG + N_NODES)
#define OFF_CURSOR (OFF_CNT + N_NODES)
#define ZERO_ELEMS (OFF_CURSOR + N_NODES)            // 150128
#define OFF_DINV   ZERO_ELEMS
#define OFF_CSRPTR (OFF_DINV + N_NODES)
#define OFF_ESRC   (OFF_CSRPTR + N_NODES + 1)
#define OFF_ENORM  (OFF_ESRC + N_EDGES)
#define OFF_BT1H   1850368                           // 256*512 bf16 = 65536 slots
#define OFF_BT1L   (OFF_BT1H + 65536)
#define OFF_BT2H   (OFF_BT1L + 65536)                // 512*512 bf16 = 131072 slots
#define OFF_BT2L   (OFF_BT2H + 131072)
#define OFF_PD     (OFF_BT2L + 131072)               // 8*PDS floats
#define OFF_XB     2643968                           // x bf16: 6.4M slots
#define OFF_A1H    (OFF_XB + 6400000)                // [M,256] bf16 hi
#define OFF_A1L    (OFF_A1H + 6400000)               // [M,256] bf16 lo
#define OFF_A2H    OFF_A1H                           // [M,512] bf16 hi (a1 dead)
#define OFF_A2L    (OFF_A1H + 12800000)              // [M,512] bf16 lo
#define OFF_H1B    (OFF_A2L + 12800000)              // h1 bf16 [M,512]

// ---------------- helpers ----------------

static __device__ inline unsigned short f2bf(float f) {   // RTN-even
    unsigned int u = __float_as_uint(f);
    return (unsigned short)((u + 0x7fff + ((u >> 16) & 1)) >> 16);
}
static __device__ inline float bf2f(unsigned short b) {
    return __uint_as_float(((unsigned int)b) << 16);
}
static __device__ inline void split_bf16(float v, unsigned short& hi, unsigned short& lo) {
    hi = f2bf(v);
    lo = f2bf(v - bf2f(hi));
}
static __device__ inline float bflo(unsigned int u) { return __uint_as_float(u << 16); }
static __device__ inline float bfhi(unsigned int u) { return __uint_as_float(u & 0xFFFF0000u); }

// ---------------- CSR build ----------------

__global__ __launch_bounds__(256) void k_deg_cnt(const int* __restrict__ src,
                                                 const int* __restrict__ dst,
                                                 const float* __restrict__ ew,
                                                 float* __restrict__ deg,
                                                 int* __restrict__ cnt) {
    int e = blockIdx.x * blockDim.x + threadIdx.x;
    if (e >= N_EDGES) return;
    int d = dst[e];
    atomicAdd(&deg[d], ew[e]);
    atomicAdd(&cnt[d], 1);
}

__global__ __launch_bounds__(256) void k_dinv(const float* __restrict__ deg,
                                              float* __restrict__ dinv) {
    int i = blockIdx.x * blockDim.x + threadIdx.x;
    if (i >= N_NODES) return;
    dinv[i] = 1.0f / sqrtf(deg[i] + 1.0f);
}

__global__ __launch_bounds__(1024) void k_scan(const int* __restrict__ cnt,
                                               int* __restrict__ ptr, int n) {
    __shared__ int wsum[16];
    __shared__ int carry;
    int tid = threadIdx.x, lane = tid & 63, wid = tid >> 6;
    if (tid == 0) carry = 0;
    __syncthreads();
    for (int base = 0; base < n; base += 1024) {
        int i = base + tid;
        int v = (i < n) ? cnt[i] : 0;
        int incl = v;
        #pragma unroll
        for (int off = 1; off < 64; off <<= 1) {
            int t = __shfl_up(incl, off);
            if (lane >= off) incl += t;
        }
        if (lane == 63) wsum[wid] = incl;
        __syncthreads();
        if (tid == 0) {
            int run = carry;
            #pragma unroll
            for (int k = 0; k < 16; ++k) { int t = wsum[k]; wsum[k] = run; run += t; }
            carry = run;
        }
        __syncthreads();
        if (i < n) ptr[i] = wsum[wid] + incl - v;
        __syncthreads();
    }
    if (threadIdx.x == 0) ptr[n] = carry;
}

__global__ __launch_bounds__(256) void k_fill(const int* __restrict__ src,
                                              const int* __restrict__ dst,
                                              const float* __restrict__ ew,
                                              const float* __restrict__ dinv,
                                              const int* __restrict__ csrptr,
                                              int* __restrict__ cursor,
                                              int* __restrict__ esrc,
                                              float* __restrict__ enorm) {
    int e = blockIdx.x * blockDim.x + threadIdx.x;
    if (e >= N_EDGES) return;
    int s = src[e], d = dst[e];
    int pos = csrptr[d] + atomicAdd(&cursor[d], 1);
    esrc[pos] = s;
    enorm[pos] = dinv[s] * ew[e] * dinv[d];
}

// ---------------- converts ----------------

template <int K>
__global__ __launch_bounds__(256) void k_convw(const float* __restrict__ W,
                                               unsigned short* __restrict__ BTh,
                                               unsigned short* __restrict__ BTl) {
    int idx = blockIdx.x * 256 + threadIdx.x;
    if (idx >= K * 512) return;
    int k = idx >> 9, n = idx & 511;
    unsigned short h, l;
    split_bf16(W[idx], h, l);
    BTh[(size_t)n * K + k] = h;
    BTl[(size_t)n * K + k] = l;
}

__global__ __launch_bounds__(256) void k_convx(const float* __restrict__ X,
                                               unsigned short* __restrict__ Xb, int n4) {
    int idx = blockIdx.x * 256 + threadIdx.x;
    if (idx >= n4) return;
    float4 v = ((const float4*)X)[idx];
    uint2 p;
    p.x = (unsigned int)f2bf(v.x) | ((unsigned int)f2bf(v.y) << 16);
    p.y = (unsigned int)f2bf(v.z) | ((unsigned int)f2bf(v.w) << 16);
    ((uint2*)Xb)[idx] = p;
}

// ---------------- aggregation (unchanged from R5) ----------------

template <int F>
__global__ __launch_bounds__(256) void k_agg(const unsigned short* __restrict__ X,
                                             const int* __restrict__ csrptr,
                                             const int* __restrict__ esrc,
                                             const float* __restrict__ enorm,
                                             const float* __restrict__ dinv,
                                             unsigned short* __restrict__ Yh,
                                             unsigned short* __restrict__ Yl) {
    constexpr int C = F / 64;
    constexpr int U = C / 2;
    int wave = (blockIdx.x * blockDim.x + threadIdx.x) >> 6;
    int lane = threadIdx.x & 63;
    if (wave >= N_NODES) return;
    int i = wave;
    float w0 = dinv[i] * dinv[i];
    float acc[C];
    {
        unsigned int u[U];
        const unsigned short* p = &X[(size_t)i * F + lane * C];
        if constexpr (U == 4) *(uint4*)u = *(const uint4*)p;
        else                  *(uint2*)u = *(const uint2*)p;
        #pragma unroll
        for (int j = 0; j < U; ++j) {
            acc[2 * j]     = w0 * bflo(u[j]);
            acc[2 * j + 1] = w0 * bfhi(u[j]);
        }
    }
    int s = csrptr[i], e = csrptr[i + 1];
    for (int j = s; j < e; ++j) {
        int sr = esrc[j];
        float w = enorm[j];
        unsigned int u[U];
        const unsigned short* p = &X[(size_t)sr * F + lane * C];
        if constexpr (U == 4) *(uint4*)u = *(const uint4*)p;
        else                  *(uint2*)u = *(const uint2*)p;
        #pragma unroll
        for (int q = 0; q < U; ++q) {
            acc[2 * q]     += w * bflo(u[q]);
            acc[2 * q + 1] += w * bfhi(u[q]);
        }
    }
    unsigned int ph[U], pl[U];
    #pragma unroll
    for (int j = 0; j < U; ++j) {
        unsigned short h0, l0, h1, l1;
        split_bf16(acc[2 * j], h0, l0);
        split_bf16(acc[2 * j + 1], h1, l1);
        ph[j] = (unsigned int)h0 | ((unsigned int)h1 << 16);
        pl[j] = (unsigned int)l0 | ((unsigned int)l1 << 16);
    }
    size_t base = (size_t)i * F + lane * C;
    if constexpr (U == 4) {
        *(uint4*)&Yh[base] = *(uint4*)ph;
        *(uint4*)&Yl[base] = *(uint4*)pl;
    } else {
        *(uint2*)&Yh[base] = *(uint2*)ph;
        *(uint2*)&Yl[base] = *(uint2*)pl;
    }
}

// ---------------- LDS-staged split-bf16 MFMA GEMM (m97/T3-minimal) ----------------
// C[M,512] = relu(A*B + bias); A hi/lo bf16 [M][K], B^T hi/lo bf16 [512][K].
// 128x128 tile, BK=32, 4 waves (2x2), wave=64x64=4x4 frags x 3 MFMA terms.
// LDS per buffer: 4 mats x [g=4][row=128][16B] = 32KB; double-buffered = 64KB.
// Staging: wave w stages matrix w via 8x global_load_lds(16B): chunk c ->
// g=c>>1, row=(c&1)*64+lane (LDS dest linear = base + lane*16, per guide).
// ds_read_b128 frag reads cover all 32 banks evenly -> conflict-free.
template <int K, bool DOT>
__global__ __launch_bounds__(256, 2) void k_mgemm(const unsigned short* __restrict__ Ah,
                                                  const unsigned short* __restrict__ Al,
                                                  const unsigned short* __restrict__ BTh,
                                                  const unsigned short* __restrict__ BTl,
                                                  const float* __restrict__ bias,
                                                  unsigned short* __restrict__ Cb,
                                                  const float* __restrict__ Wl,
                                                  float* __restrict__ pd) {
    constexpr int NT = K / 32;
    __shared__ __align__(16) unsigned short smem[2 * 4 * 4096];  // 64 KB

    int wgid = blockIdx.x;
    int rowblk = (wgid >> 5) * 8 + (wgid & 7);     // XCD swizzle: col-siblings 8 apart
    if (rowblk >= NRB) return;
    int colblk = (wgid >> 3) & 3;
    int tid = threadIdx.x, lane = tid & 63, wid = tid >> 6;
    int wm = wid >> 1, wn = wid & 1;
    int row0 = rowblk * 128 + wm * 64;
    int col0 = colblk * 128 + wn * 64;
    int l15 = lane & 15, l4 = lane >> 4;

    // staging setup: wave `wid` owns matrix `wid` (0:Ah 1:Al 2:Bh 3:Bl)
    const unsigned short* mbase = (wid == 0) ? Ah : (wid == 1) ? Al : (wid == 2) ? BTh : BTl;
    int r0 = (wid < 2) ? rowblk * 128 : colblk * 128;
    int ra = r0 + lane, rb = r0 + 64 + lane;
    if (wid < 2) {                                  // clamp A rows (last block only)
        if (ra >= N_NODES) ra = N_NODES - 1;
        if (rb >= N_NODES) rb = N_NODES - 1;
    }
    const unsigned short* gA = mbase + (size_t)ra * K;   // advanced by 32/iter
    const unsigned short* gB = mbase + (size_t)rb * K;

    f32x4 acc[4][4];
    #pragma unroll
    for (int a = 0; a < 4; ++a)
        #pragma unroll
        for (int b = 0; b < 4; ++b) acc[a][b] = (f32x4){0.f, 0.f, 0.f, 0.f};

    // stage one 32-k tile of matrix `wid` into buffer b
    auto STAGE = [&](int b) {
        unsigned short* lb = &smem[b * 16384 + wid * 4096];
        #pragma unroll
        for (int c = 0; c < 8; ++c) {
            const unsigned short* gp = ((c & 1) ? gB : gA) + (c >> 1) * 8;
            __builtin_amdgcn_global_load_lds((gas_ptr)gp, (las_ptr)(lb + c * 512), 16, 0, 0);
        }
    };

    STAGE(0);
    __syncthreads();

    for (int t = 0; t < NT; ++t) {
        int cur = t & 1;
        if (t + 1 < NT) {
            gA += 32; gB += 32;
            STAGE(cur ^ 1);
        }
        const unsigned short* sb = &smem[cur * 16384];
        bf16x8 ah[4], al[4], bh[4], bl[4];
        int aoff = l4 * 1024 + (wm * 64 + l15) * 8;
        int boff = l4 * 1024 + (wn * 64 + l15) * 8;
        #pragma unroll
        for (int mf = 0; mf < 4; ++mf) {
            ah[mf] = *(const bf16x8*)&sb[0 * 4096 + aoff + mf * 128];
            al[mf] = *(const bf16x8*)&sb[1 * 4096 + aoff + mf * 128];
        }
        #pragma unroll
        for (int nf = 0; nf < 4; ++nf) {
            bh[nf] = *(const bf16x8*)&sb[2 * 4096 + boff + nf * 128];
            bl[nf] = *(const bf16x8*)&sb[3 * 4096 + boff + nf * 128];
        }
        #pragma unroll
        for (int mf = 0; mf < 4; ++mf)
            #pragma unroll
            for (int nf = 0; nf < 4; ++nf) {
                acc[mf][nf] = __builtin_amdgcn_mfma_f32_16x16x32_bf16(ah[mf], bh[nf], acc[mf][nf], 0, 0, 0);
                acc[mf][nf] = __builtin_amdgcn_mfma_f32_16x16x32_bf16(ah[mf], bl[nf], acc[mf][nf], 0, 0, 0);
                acc[mf][nf] = __builtin_amdgcn_mfma_f32_16x16x32_bf16(al[mf], bh[nf], acc[mf][nf], 0, 0, 0);
            }
        __syncthreads();   // drains vmcnt (next tile staged) + lgkm (buf consumed)
    }

    if (!DOT) {
        #pragma unroll
        for (int mf = 0; mf < 4; ++mf)
            #pragma unroll
            for (int nf = 0; nf < 4; ++nf) {
                int c = col0 + nf * 16 + l15;
                float bv = bias[c];
                #pragma unroll
                for (int r = 0; r < 4; ++r) {
                    int row = row0 + mf * 16 + l4 * 4 + r;
                    if (row < N_NODES)
                        Cb[(size_t)row * 512 + c] = f2bf(fmaxf(acc[mf][nf][r] + bv, 0.f));
                }
            }
    } else {
        float rowsum[4][4];
        #pragma unroll
        for (int mf = 0; mf < 4; ++mf)
            #pragma unroll
            for (int r = 0; r < 4; ++r) rowsum[mf][r] = 0.f;
        #pragma unroll
        for (int nf = 0; nf < 4; ++nf) {
            int c = col0 + nf * 16 + l15;
            float bv = bias[c];
            float wv = Wl[c];
            #pragma unroll
            for (int mf = 0; mf < 4; ++mf)
                #pragma unroll
                for (int r = 0; r < 4; ++r)
                    rowsum[mf][r] += fmaxf(acc[mf][nf][r] + bv, 0.f) * wv;
        }
        #pragma unroll
        for (int mf = 0; mf < 4; ++mf)
            #pragma unroll
            for (int r = 0; r < 4; ++r) {
                float v = rowsum[mf][r];
                #pragma unroll
                for (int mask = 1; mask <= 8; mask <<= 1) v += __shfl_xor(v, mask);
                if (l15 == 0) {
                    int row = row0 + mf * 16 + l4 * 4 + r;
                    if (row < N_NODES)
                        pd[(size_t)(colblk * 2 + wn) * PDS + row] = v;
                }
            }
    }
}

// ---------------- pool ----------------

__global__ __launch_bounds__(256) void k_gpool(const float* __restrict__ pd,
                                               const int* __restrict__ batch,
                                               const float* __restrict__ bl,
                                               float* __restrict__ out) {
    int g = blockIdx.x;
    int tid = threadIdx.x;
    float s = 0.f;
    int c = 0;
    for (int i = tid; i < N_NODES; i += 256) {
        if (batch[i] == g) {
            float v = 0.f;
            #pragma unroll
            for (int p = 0; p < 8; ++p) v += pd[(size_t)p * PDS + i];
            s += v;
            c += 1;
        }
    }
    __shared__ float ss[4];
    __shared__ int sc[4];
    int lane = tid & 63, wid = tid >> 6;
    #pragma unroll
    for (int off = 32; off > 0; off >>= 1) {
        s += __shfl_down(s, off);
        c += __shfl_down(c, off);
    }
    if (lane == 0) { ss[wid] = s; sc[wid] = c; }
    __syncthreads();
    if (tid == 0) {
        float S = ss[0] + ss[1] + ss[2] + ss[3];
        int C = sc[0] + sc[1] + sc[2] + sc[3];
        out[g] = S / fmaxf((float)C, 1.0f) + bl[0];
    }
}

// ---------------- launch ----------------

extern "C" void kernel_launch(void* const* d_in, const int* in_sizes, int n_in,
                              void* d_out, int out_size, void* d_ws, size_t ws_size,
                              hipStream_t stream) {
    const float* x  = (const float*)d_in[0];
    const int* ei   = (const int*)d_in[1];
    const float* ew = (const float*)d_in[2];
    const int* batch= (const int*)d_in[3];
    const float* W1 = (const float*)d_in[4];
    const float* b1 = (const float*)d_in[5];
    const float* W2 = (const float*)d_in[6];
    const float* b2 = (const float*)d_in[7];
    const float* Wl = (const float*)d_in[8];
    const float* bl = (const float*)d_in[9];
    float* out = (float*)d_out;

    const int* src = ei;
    const int* dst = ei + N_EDGES;

    float* ws = (float*)d_ws;
    float* deg    = ws + OFF_DEG;
    int*   cnt    = (int*)(ws + OFF_CNT);
    int*   cursor = (int*)(ws + OFF_CURSOR);
    float* dinv   = ws + OFF_DINV;
    int*   csrptr = (int*)(ws + OFF_CSRPTR);
    int*   esrc   = (int*)(ws + OFF_ESRC);
    float* enorm  = ws + OFF_ENORM;
    unsigned short* bt1h = (unsigned short*)(ws + OFF_BT1H);
    unsigned short* bt1l = (unsigned short*)(ws + OFF_BT1L);
    unsigned short* bt2h = (unsigned short*)(ws + OFF_BT2H);
    unsigned short* bt2l = (unsigned short*)(ws + OFF_BT2L);
    float* pd     = ws + OFF_PD;
    unsigned short* xb  = (unsigned short*)(ws + OFF_XB);
    unsigned short* a1h = (unsigned short*)(ws + OFF_A1H);
    unsigned short* a1l = (unsigned short*)(ws + OFF_A1L);
    unsigned short* a2h = (unsigned short*)(ws + OFF_A2H);
    unsigned short* a2l = (unsigned short*)(ws + OFF_A2L);
    unsigned short* h1b = (unsigned short*)(ws + OFF_H1B);

    hipMemsetAsync(ws, 0, (size_t)ZERO_ELEMS * 4, stream);

    int eb = (N_EDGES + 255) / 256;
    int nb = (N_NODES + 255) / 256;
    int wb = (N_NODES * 64 + 255) / 256;

    k_deg_cnt<<<eb, 256, 0, stream>>>(src, dst, ew, deg, cnt);
    k_dinv<<<nb, 256, 0, stream>>>(deg, dinv);
    k_scan<<<1, 1024, 0, stream>>>(cnt, csrptr, N_NODES);
    k_fill<<<eb, 256, 0, stream>>>(src, dst, ew, dinv, csrptr, cursor, esrc, enorm);

    k_convw<IN_CH><<<(IN_CH * 512 + 255) / 256, 256, 0, stream>>>(W1, bt1h, bt1l);
    k_convw<HID><<<(HID * 512 + 255) / 256, 256, 0, stream>>>(W2, bt2h, bt2l);
    k_convx<<<(N_NODES * IN_CH / 4 + 255) / 256, 256, 0, stream>>>(x, xb, N_NODES * IN_CH / 4);

    // layer 1
    k_agg<IN_CH><<<wb, 256, 0, stream>>>(xb, csrptr, esrc, enorm, dinv, a1h, a1l);
    k_mgemm<IN_CH, false><<<MG_GRID, 256, 0, stream>>>(a1h, a1l, bt1h, bt1l, b1, h1b, nullptr, nullptr);

    // layer 2 (+ fused dot with Wl)
    k_agg<HID><<<wb, 256, 0, stream>>>(h1b, csrptr, esrc, enorm, dinv, a2h, a2l);
    k_mgemm<HID, true><<<MG_GRID, 256, 0, stream>>>(a2h, a2l, bt2h, bt2l, b2, nullptr, Wl, pd);

    // pool + head
    k_gpool<<<N_GRAPHS, 256, 0, stream>>>(pd, batch, bl, out);
}

// Round 11
// 778.697 us; speedup vs baseline: 2.0142x; 1.1810x over previous
//
#include <hip/hip_runtime.h>
#include <hip/hip_bf16.h>

// ---------------------------------------------------------------------------
// GNNRegression: 2-layer GCN + global mean pool + linear head. MI355X gfx950.
// R3: atomic-free pool (1568->1245us).
// R4: split-bf16 MFMA GEMM, fused dot epilogue (1245->1066us).
// R5: bf16 gather operands + XCD swizzle (1066->937us).
// R6: LDS-staged mgemm (m97-style). R9 result: 235->232us, MfmaUtil 14% --
//     structure change was NEUTRAL -> limiter is envelope (20% occupancy x
//     exposed latency, 3 generations), not the inner loop.
// R9: drop A-lo plane (A inputs already carry bf16-level noise from x/h1
//     storage -- hi/lo on A preserved precision that was already lost):
//     C = A*Bh + A*Bl (2 MFMA terms). A-traffic and agg writes halve,
//     MFMA work -33%, LDS 64->48KB -> 3 blocks/CU (occ 20->30%),
//     generations 3.05->2.04.
// Workspace end = OFF_H1B + 12.8M slots = 34,643,968 slots (~138.6 MB).
// ---------------------------------------------------------------------------

#define N_NODES 50000
#define N_EDGES 800000
#define IN_CH   256
#define HID     512
#define N_GRAPHS 64
#define PDS     50048   // pd row stride
#define NRB     391     // row blocks of 128
#define MG_GRID 1568    // 392 rowblk-slots * 4 colblks (tail blocks early-exit)

typedef short bf16x8 __attribute__((ext_vector_type(8)));
typedef float f32x4  __attribute__((ext_vector_type(4)));

typedef const __attribute__((address_space(1))) void* gas_ptr;
typedef __attribute__((address_space(3))) void* las_ptr;

// ---------------- workspace layout (4-byte slots) ----------------
#define OFF_DEG    128
#define OFF_CNT    (OFF_DEG + N_NODES)
#define OFF_CURSOR (OFF_CNT + N_NODES)
#define ZERO_ELEMS (OFF_CURSOR + N_NODES)            // 150128
#define OFF_DINV   ZERO_ELEMS
#define OFF_CSRPTR (OFF_DINV + N_NODES)
#define OFF_ESRC   (OFF_CSRPTR + N_NODES + 1)
#define OFF_ENORM  (OFF_ESRC + N_EDGES)
#define OFF_BT1H   1850368                           // 256*512 bf16 = 65536 slots
#define OFF_BT1L   (OFF_BT1H + 65536)
#define OFF_BT2H   (OFF_BT1L + 65536)                // 512*512 bf16 = 131072 slots
#define OFF_BT2L   (OFF_BT2H + 131072)
#define OFF_PD     (OFF_BT2L + 131072)               // 8*PDS floats
#define OFF_XB     2643968                           // x bf16 [M,256]: 6.4M slots
#define OFF_A      (OFF_XB + 6400000)                // A1 [M,256] (6.4M) / A2 [M,512] (12.8M slots)
#define OFF_H1B    (OFF_A + 12800000)                // h1 bf16 [M,512]: 12.8M slots

// ---------------- helpers ----------------

static __device__ inline unsigned short f2bf(float f) {   // RTN-even
    unsigned int u = __float_as_uint(f);
    return (unsigned short)((u + 0x7fff + ((u >> 16) & 1)) >> 16);
}
static __device__ inline float bf2f(unsigned short b) {
    return __uint_as_float(((unsigned int)b) << 16);
}
static __device__ inline void split_bf16(float v, unsigned short& hi, unsigned short& lo) {
    hi = f2bf(v);
    lo = f2bf(v - bf2f(hi));
}
static __device__ inline float bflo(unsigned int u) { return __uint_as_float(u << 16); }
static __device__ inline float bfhi(unsigned int u) { return __uint_as_float(u & 0xFFFF0000u); }

// ---------------- CSR build ----------------

__global__ __launch_bounds__(256) void k_deg_cnt(const int* __restrict__ src,
                                                 const int* __restrict__ dst,
                                                 const float* __restrict__ ew,
                                                 float* __restrict__ deg,
                                                 int* __restrict__ cnt) {
    int e = blockIdx.x * blockDim.x + threadIdx.x;
    if (e >= N_EDGES) return;
    int d = dst[e];
    atomicAdd(&deg[d], ew[e]);
    atomicAdd(&cnt[d], 1);
}

__global__ __launch_bounds__(256) void k_dinv(const float* __restrict__ deg,
                                              float* __restrict__ dinv) {
    int i = blockIdx.x * blockDim.x + threadIdx.x;
    if (i >= N_NODES) return;
    dinv[i] = 1.0f / sqrtf(deg[i] + 1.0f);
}

__global__ __launch_bounds__(1024) void k_scan(const int* __restrict__ cnt,
                                               int* __restrict__ ptr, int n) {
    __shared__ int wsum[16];
    __shared__ int carry;
    int tid = threadIdx.x, lane = tid & 63, wid = tid >> 6;
    if (tid == 0) carry = 0;
    __syncthreads();
    for (int base = 0; base < n; base += 1024) {
        int i = base + tid;
        int v = (i < n) ? cnt[i] : 0;
        int incl = v;
        #pragma unroll
        for (int off = 1; off < 64; off <<= 1) {
            int t = __shfl_up(incl, off);
            if (lane >= off) incl += t;
        }
        if (lane == 63) wsum[wid] = incl;
        __syncthreads();
        if (tid == 0) {
            int run = carry;
            #pragma unroll
            for (int k = 0; k < 16; ++k) { int t = wsum[k]; wsum[k] = run; run += t; }
            carry = run;
        }
        __syncthreads();
        if (i < n) ptr[i] = wsum[wid] + incl - v;
        __syncthreads();
    }
    if (threadIdx.x == 0) ptr[n] = carry;
}

__global__ __launch_bounds__(256) void k_fill(const int* __restrict__ src,
                                              const int* __restrict__ dst,
                                              const float* __restrict__ ew,
                                              const float* __restrict__ dinv,
                                              const int* __restrict__ csrptr,
                                              int* __restrict__ cursor,
                                              int* __restrict__ esrc,
                                              float* __restrict__ enorm) {
    int e = blockIdx.x * blockDim.x + threadIdx.x;
    if (e >= N_EDGES) return;
    int s = src[e], d = dst[e];
    int pos = csrptr[d] + atomicAdd(&cursor[d], 1);
    esrc[pos] = s;
    enorm[pos] = dinv[s] * ew[e] * dinv[d];
}

// ---------------- converts ----------------

template <int K>
__global__ __launch_bounds__(256) void k_convw(const float* __restrict__ W,
                                               unsigned short* __restrict__ BTh,
                                               unsigned short* __restrict__ BTl) {
    int idx = blockIdx.x * 256 + threadIdx.x;
    if (idx >= K * 512) return;
    int k = idx >> 9, n = idx & 511;
    unsigned short h, l;
    split_bf16(W[idx], h, l);
    BTh[(size_t)n * K + k] = h;
    BTl[(size_t)n * K + k] = l;
}

__global__ __launch_bounds__(256) void k_convx(const float* __restrict__ X,
                                               unsigned short* __restrict__ Xb, int n4) {
    int idx = blockIdx.x * 256 + threadIdx.x;
    if (idx >= n4) return;
    float4 v = ((const float4*)X)[idx];
    uint2 p;
    p.x = (unsigned int)f2bf(v.x) | ((unsigned int)f2bf(v.y) << 16);
    p.y = (unsigned int)f2bf(v.z) | ((unsigned int)f2bf(v.w) << 16);
    ((uint2*)Xb)[idx] = p;
}

// ---------------- aggregation: Y = A_norm X (X bf16), out single bf16 ----------------

template <int F>
__global__ __launch_bounds__(256) void k_agg(const unsigned short* __restrict__ X,
                                             const int* __restrict__ csrptr,
                                             const int* __restrict__ esrc,
                                             const float* __restrict__ enorm,
                                             const float* __restrict__ dinv,
                                             unsigned short* __restrict__ Yb) {
    constexpr int C = F / 64;
    constexpr int U = C / 2;
    int wave = (blockIdx.x * blockDim.x + threadIdx.x) >> 6;
    int lane = threadIdx.x & 63;
    if (wave >= N_NODES) return;
    int i = wave;
    float w0 = dinv[i] * dinv[i];
    float acc[C];
    {
        unsigned int u[U];
        const unsigned short* p = &X[(size_t)i * F + lane * C];
        if constexpr (U == 4) *(uint4*)u = *(const uint4*)p;
        else                  *(uint2*)u = *(const uint2*)p;
        #pragma unroll
        for (int j = 0; j < U; ++j) {
            acc[2 * j]     = w0 * bflo(u[j]);
            acc[2 * j + 1] = w0 * bfhi(u[j]);
        }
    }
    int s = csrptr[i], e = csrptr[i + 1];
    for (int j = s; j < e; ++j) {
        int sr = esrc[j];
        float w = enorm[j];
        unsigned int u[U];
        const unsigned short* p = &X[(size_t)sr * F + lane * C];
        if constexpr (U == 4) *(uint4*)u = *(const uint4*)p;
        else                  *(uint2*)u = *(const uint2*)p;
        #pragma unroll
        for (int q = 0; q < U; ++q) {
            acc[2 * q]     += w * bflo(u[q]);
            acc[2 * q + 1] += w * bfhi(u[q]);
        }
    }
    unsigned int pk[U];
    #pragma unroll
    for (int j = 0; j < U; ++j)
        pk[j] = (unsigned int)f2bf(acc[2 * j]) | ((unsigned int)f2bf(acc[2 * j + 1]) << 16);
    size_t base = (size_t)i * F + lane * C;
    if constexpr (U == 4) *(uint4*)&Yb[base] = *(uint4*)pk;
    else                  *(uint2*)&Yb[base] = *(uint2*)pk;
}

// ---------------- LDS-staged 2-term bf16 MFMA GEMM ----------------
// C[M,512] = relu(A*(Bh+Bl) + bias); A single bf16 [M][K], B^T hi/lo [512][K].
// 128x128 tile, BK=32, 4 waves (2x2). LDS/buffer: A 8KB + Bh 8KB + Bl 8KB =
// 24KB, double-buffered 48KB -> 3 blocks/CU. Staging: wave0/1 = A row-halves,
// wave2 = Bh, wave3 = Bl, global_load_lds width=16, linear LDS [g][row][16B].
template <int K, bool DOT>
__global__ __launch_bounds__(256, 3) void k_mgemm(const unsigned short* __restrict__ Ab,
                                                  const unsigned short* __restrict__ BTh,
                                                  const unsigned short* __restrict__ BTl,
                                                  const float* __restrict__ bias,
                                                  unsigned short* __restrict__ Cb,
                                                  const float* __restrict__ Wl,
                                                  float* __restrict__ pd) {
    constexpr int NT = K / 32;
    __shared__ __align__(16) unsigned short smem[2 * 12288];  // 48 KB

    int wgid = blockIdx.x;
    int rowblk = (wgid >> 5) * 8 + (wgid & 7);     // XCD swizzle: col-siblings 8 apart
    if (rowblk >= NRB) return;
    int colblk = (wgid >> 3) & 3;
    int tid = threadIdx.x, lane = tid & 63, wid = tid >> 6;
    int wm = wid >> 1, wn = wid & 1;
    int row0 = rowblk * 128 + wm * 64;
    int col0 = colblk * 128 + wn * 64;
    int l15 = lane & 15, l4 = lane >> 4;

    // staging role per wave: 0/1 -> A rows [wid*64, wid*64+64); 2 -> Bh; 3 -> Bl
    const unsigned short* gA;
    const unsigned short* gB = BTh;               // second row-set, waves 2/3 only
    if (wid < 2) {
        int r = rowblk * 128 + wid * 64 + lane;
        if (r >= N_NODES) r = N_NODES - 1;        // clamped read, store-guarded
        gA = Ab + (size_t)r * K;
    } else {
        const unsigned short* mb = (wid == 2) ? BTh : BTl;
        gA = mb + (size_t)(colblk * 128 + lane) * K;
        gB = mb + (size_t)(colblk * 128 + 64 + lane) * K;
    }

    f32x4 acc[4][4];
    #pragma unroll
    for (int a = 0; a < 4; ++a)
        #pragma unroll
        for (int b = 0; b < 4; ++b) acc[a][b] = (f32x4){0.f, 0.f, 0.f, 0.f};

    // stage one 32-k tile into buffer b: LDS layout (ushorts)
    //   A:  g*1024 + row*8          (rows 0..127)
    //   Bh: 4096 + g*1024 + col*8
    //   Bl: 8192 + g*1024 + col*8
    auto STAGE = [&](int b) {
        unsigned short* lb = &smem[b * 12288];
        if (wid < 2) {
            #pragma unroll
            for (int g = 0; g < 4; ++g)
                __builtin_amdgcn_global_load_lds((gas_ptr)(gA + g * 8),
                                                 (las_ptr)(lb + g * 1024 + wid * 512), 16, 0, 0);
        } else {
            unsigned short* mb = lb + (wid - 1) * 4096;
            #pragma unroll
            for (int g = 0; g < 4; ++g) {
                __builtin_amdgcn_global_load_lds((gas_ptr)(gA + g * 8),
                                                 (las_ptr)(mb + g * 1024), 16, 0, 0);
                __builtin_amdgcn_global_load_lds((gas_ptr)(gB + g * 8),
                                                 (las_ptr)(mb + g * 1024 + 512), 16, 0, 0);
            }
        }
    };

    STAGE(0);
    __syncthreads();

    for (int t = 0; t < NT; ++t) {
        int cur = t & 1;
        if (t + 1 < NT) {
            gA += 32;
            if (wid >= 2) gB += 32;
            STAGE(cur ^ 1);
        }
        const unsigned short* sb = &smem[cur * 12288];
        int aoff = l4 * 1024 + (wm * 64 + l15) * 8;
        int boff = l4 * 1024 + (wn * 64 + l15) * 8;
        bf16x8 a[4];
        #pragma unroll
        for (int mf = 0; mf < 4; ++mf) a[mf] = *(const bf16x8*)&sb[aoff + mf * 128];
        #pragma unroll
        for (int nf = 0; nf < 4; ++nf) {
            bf16x8 bh = *(const bf16x8*)&sb[4096 + boff + nf * 128];
            bf16x8 bl = *(const bf16x8*)&sb[8192 + boff + nf * 128];
            #pragma unroll
            for (int mf = 0; mf < 4; ++mf) {
                acc[mf][nf] = __builtin_amdgcn_mfma_f32_16x16x32_bf16(a[mf], bh, acc[mf][nf], 0, 0, 0);
                acc[mf][nf] = __builtin_amdgcn_mfma_f32_16x16x32_bf16(a[mf], bl, acc[mf][nf], 0, 0, 0);
            }
        }
        __syncthreads();   // drains vmcnt (next tile staged) + lgkm (buf consumed)
    }

    if (!DOT) {
        #pragma unroll
        for (int mf = 0; mf < 4; ++mf)
            #pragma unroll
            for (int nf = 0; nf < 4; ++nf) {
                int c = col0 + nf * 16 + l15;
                float bv = bias[c];
                #pragma unroll
                for (int r = 0; r < 4; ++r) {
                    int row = row0 + mf * 16 + l4 * 4 + r;
                    if (row < N_NODES)
                        Cb[(size_t)row * 512 + c] = f2bf(fmaxf(acc[mf][nf][r] + bv, 0.f));
                }
            }
    } else {
        float rowsum[4][4];
        #pragma unroll
        for (int mf = 0; mf < 4; ++mf)
            #pragma unroll
            for (int r = 0; r < 4; ++r) rowsum[mf][r] = 0.f;
        #pragma unroll
        for (int nf = 0; nf < 4; ++nf) {
            int c = col0 + nf * 16 + l15;
            float bv = bias[c];
            float wv = Wl[c];
            #pragma unroll
            for (int mf = 0; mf < 4; ++mf)
                #pragma unroll
                for (int r = 0; r < 4; ++r)
                    rowsum[mf][r] += fmaxf(acc[mf][nf][r] + bv, 0.f) * wv;
        }
        #pragma unroll
        for (int mf = 0; mf < 4; ++mf)
            #pragma unroll
            for (int r = 0; r < 4; ++r) {
                float v = rowsum[mf][r];
                #pragma unroll
                for (int mask = 1; mask <= 8; mask <<= 1) v += __shfl_xor(v, mask);
                if (l15 == 0) {
                    int row = row0 + mf * 16 + l4 * 4 + r;
                    if (row < N_NODES)
                        pd[(size_t)(colblk * 2 + wn) * PDS + row] = v;
                }
            }
    }
}

// ---------------- pool ----------------

__global__ __launch_bounds__(256) void k_gpool(const float* __restrict__ pd,
                                               const int* __restrict__ batch,
                                               const float* __restrict__ bl,
                                               float* __restrict__ out) {
    int g = blockIdx.x;
    int tid = threadIdx.x;
    float s = 0.f;
    int c = 0;
    for (int i = tid; i < N_NODES; i += 256) {
        if (batch[i] == g) {
            float v = 0.f;
            #pragma unroll
            for (int p = 0; p < 8; ++p) v += pd[(size_t)p * PDS + i];
            s += v;
            c += 1;
        }
    }
    __shared__ float ss[4];
    __shared__ int sc[4];
    int lane = tid & 63, wid = tid >> 6;
    #pragma unroll
    for (int off = 32; off > 0; off >>= 1) {
        s += __shfl_down(s, off);
        c += __shfl_down(c, off);
    }
    if (lane == 0) { ss[wid] = s; sc[wid] = c; }
    __syncthreads();
    if (tid == 0) {
        float S = ss[0] + ss[1] + ss[2] + ss[3];
        int C = sc[0] + sc[1] + sc[2] + sc[3];
        out[g] = S / fmaxf((float)C, 1.0f) + bl[0];
    }
}

// ---------------- launch ----------------

extern "C" void kernel_launch(void* const* d_in, const int* in_sizes, int n_in,
                              void* d_out, int out_size, void* d_ws, size_t ws_size,
                              hipStream_t stream) {
    const float* x  = (const float*)d_in[0];
    const int* ei   = (const int*)d_in[1];
    const float* ew = (const float*)d_in[2];
    const int* batch= (const int*)d_in[3];
    const float* W1 = (const float*)d_in[4];
    const float* b1 = (const float*)d_in[5];
    const float* W2 = (const float*)d_in[6];
    const float* b2 = (const float*)d_in[7];
    const float* Wl = (const float*)d_in[8];
    const float* bl = (const float*)d_in[9];
    float* out = (float*)d_out;

    const int* src = ei;
    const int* dst = ei + N_EDGES;

    float* ws = (float*)d_ws;
    float* deg    = ws + OFF_DEG;
    int*   cnt    = (int*)(ws + OFF_CNT);
    int*   cursor = (int*)(ws + OFF_CURSOR);
    float* dinv   = ws + OFF_DINV;
    int*   csrptr = (int*)(ws + OFF_CSRPTR);
    int*   esrc   = (int*)(ws + OFF_ESRC);
    float* enorm  = ws + OFF_ENORM;
    unsigned short* bt1h = (unsigned short*)(ws + OFF_BT1H);
    unsigned short* bt1l = (unsigned short*)(ws + OFF_BT1L);
    unsigned short* bt2h = (unsigned short*)(ws + OFF_BT2H);
    unsigned short* bt2l = (unsigned short*)(ws + OFF_BT2L);
    float* pd     = ws + OFF_PD;
    unsigned short* xb  = (unsigned short*)(ws + OFF_XB);
    unsigned short* a1  = (unsigned short*)(ws + OFF_A);   // [M,256] bf16
    unsigned short* a2  = (unsigned short*)(ws + OFF_A);   // [M,512] bf16 (a1 dead by then)
    unsigned short* h1b = (unsigned short*)(ws + OFF_H1B); // [M,512] bf16

    hipMemsetAsync(ws, 0, (size_t)ZERO_ELEMS * 4, stream);

    int eb = (N_EDGES + 255) / 256;
    int nb = (N_NODES + 255) / 256;
    int wb = (N_NODES * 64 + 255) / 256;

    k_deg_cnt<<<eb, 256, 0, stream>>>(src, dst, ew, deg, cnt);
    k_dinv<<<nb, 256, 0, stream>>>(deg, dinv);
    k_scan<<<1, 1024, 0, stream>>>(cnt, csrptr, N_NODES);
    k_fill<<<eb, 256, 0, stream>>>(src, dst, ew, dinv, csrptr, cursor, esrc, enorm);

    k_convw<IN_CH><<<(IN_CH * 512 + 255) / 256, 256, 0, stream>>>(W1, bt1h, bt1l);
    k_convw<HID><<<(HID * 512 + 255) / 256, 256, 0, stream>>>(W2, bt2h, bt2l);
    k_convx<<<(N_NODES * IN_CH / 4 + 255) / 256, 256, 0, stream>>>(x, xb, N_NODES * IN_CH / 4);

    // layer 1
    k_agg<IN_CH><<<wb, 256, 0, stream>>>(xb, csrptr, esrc, enorm, dinv, a1);
    k_mgemm<IN_CH, false><<<MG_GRID, 256, 0, stream>>>(a1, bt1h, bt1l, b1, h1b, nullptr, nullptr);

    // layer 2 (+ fused dot with Wl)
    k_agg<HID><<<wb, 256, 0, stream>>>(h1b, csrptr, esrc, enorm, dinv, a2);
    k_mgemm<HID, true><<<MG_GRID, 256, 0, stream>>>(a2, bt2h, bt2l, b2, nullptr, Wl, pd);

    // pool + head
    k_gpool<<<N_GRAPHS, 256, 0, stream>>>(pd, batch, bl, out);
}

// Round 12
// 717.080 us; speedup vs baseline: 2.1873x; 1.0859x over previous
//
#include <hip/hip_runtime.h>
#include <hip/hip_bf16.h>

// ---------------------------------------------------------------------------
// GNNRegression: 2-layer GCN + global mean pool + linear head. MI355X gfx950.
// R3: atomic-free pool (1568->1245us).    R4: split-bf16 MFMA GEMM (->1066us).
// R5: bf16 gather + XCD swizzle (->937us).
// R6/R9: LDS-staged 2-term GEMM, A single-bf16, 3 blk/CU (->779us, mgemm2 140us,
//        MfmaUtil 15%: 2-phase stage+drain dominates step time, B-staging 2x A).
// R11: taller tile 256x128, 8 waves (2 col x 4 row of 64x64 wave-tiles):
//      B-staging per A-row halves, 16 waves/CU (2 blk x 8 w, 64KB LDS),
//      generations 2.04->1.53. Same verified 2-phase loop semantics.
// ---------------------------------------------------------------------------

#define N_NODES 50000
#define N_EDGES 800000
#define IN_CH   256
#define HID     512
#define N_GRAPHS 64
#define PDS     50048   // pd row stride
#define NRB     196     // row blocks of 256
#define MG_GRID 800     // ceil(196/8)*8=200 rowblk-slots * 4 colblks

typedef short bf16x8 __attribute__((ext_vector_type(8)));
typedef float f32x4  __attribute__((ext_vector_type(4)));

typedef const __attribute__((address_space(1))) void* gas_ptr;
typedef __attribute__((address_space(3))) void* las_ptr;

// ---------------- workspace layout (4-byte slots) ----------------
#define OFF_DEG    128
#define OFF_CNT    (OFF_DEG + N_NODES)
#define OFF_CURSOR (OFF_CNT + N_NODES)
#define ZERO_ELEMS (OFF_CURSOR + N_NODES)            // 150128
#define OFF_DINV   ZERO_ELEMS
#define OFF_CSRPTR (OFF_DINV + N_NODES)
#define OFF_ESRC   (OFF_CSRPTR + N_NODES + 1)
#define OFF_ENORM  (OFF_ESRC + N_EDGES)
#define OFF_BT1H   1850368                           // 256*512 bf16 = 65536 slots
#define OFF_BT1L   (OFF_BT1H + 65536)
#define OFF_BT2H   (OFF_BT1L + 65536)                // 512*512 bf16 = 131072 slots
#define OFF_BT2L   (OFF_BT2H + 131072)
#define OFF_PD     (OFF_BT2L + 131072)               // 8*PDS floats
#define OFF_XB     2643968                           // x bf16 [M,256]: 6.4M slots
#define OFF_A      (OFF_XB + 6400000)                // A1 [M,256] / A2 [M,512] (12.8M slots)
#define OFF_H1B    (OFF_A + 12800000)                // h1 bf16 [M,512]: 12.8M slots

// ---------------- helpers ----------------

static __device__ inline unsigned short f2bf(float f) {   // RTN-even
    unsigned int u = __float_as_uint(f);
    return (unsigned short)((u + 0x7fff + ((u >> 16) & 1)) >> 16);
}
static __device__ inline float bf2f(unsigned short b) {
    return __uint_as_float(((unsigned int)b) << 16);
}
static __device__ inline void split_bf16(float v, unsigned short& hi, unsigned short& lo) {
    hi = f2bf(v);
    lo = f2bf(v - bf2f(hi));
}
static __device__ inline float bflo(unsigned int u) { return __uint_as_float(u << 16); }
static __device__ inline float bfhi(unsigned int u) { return __uint_as_float(u & 0xFFFF0000u); }

// ---------------- CSR build ----------------

__global__ __launch_bounds__(256) void k_deg_cnt(const int* __restrict__ src,
                                                 const int* __restrict__ dst,
                                                 const float* __restrict__ ew,
                                                 float* __restrict__ deg,
                                                 int* __restrict__ cnt) {
    int e = blockIdx.x * blockDim.x + threadIdx.x;
    if (e >= N_EDGES) return;
    int d = dst[e];
    atomicAdd(&deg[d], ew[e]);
    atomicAdd(&cnt[d], 1);
}

__global__ __launch_bounds__(256) void k_dinv(const float* __restrict__ deg,
                                              float* __restrict__ dinv) {
    int i = blockIdx.x * blockDim.x + threadIdx.x;
    if (i >= N_NODES) return;
    dinv[i] = 1.0f / sqrtf(deg[i] + 1.0f);
}

__global__ __launch_bounds__(1024) void k_scan(const int* __restrict__ cnt,
                                               int* __restrict__ ptr, int n) {
    __shared__ int wsum[16];
    __shared__ int carry;
    int tid = threadIdx.x, lane = tid & 63, wid = tid >> 6;
    if (tid == 0) carry = 0;
    __syncthreads();
    for (int base = 0; base < n; base += 1024) {
        int i = base + tid;
        int v = (i < n) ? cnt[i] : 0;
        int incl = v;
        #pragma unroll
        for (int off = 1; off < 64; off <<= 1) {
            int t = __shfl_up(incl, off);
            if (lane >= off) incl += t;
        }
        if (lane == 63) wsum[wid] = incl;
        __syncthreads();
        if (tid == 0) {
            int run = carry;
            #pragma unroll
            for (int k = 0; k < 16; ++k) { int t = wsum[k]; wsum[k] = run; run += t; }
            carry = run;
        }
        __syncthreads();
        if (i < n) ptr[i] = wsum[wid] + incl - v;
        __syncthreads();
    }
    if (threadIdx.x == 0) ptr[n] = carry;
}

__global__ __launch_bounds__(256) void k_fill(const int* __restrict__ src,
                                              const int* __restrict__ dst,
                                              const float* __restrict__ ew,
                                              const float* __restrict__ dinv,
                                              const int* __restrict__ csrptr,
                                              int* __restrict__ cursor,
                                              int* __restrict__ esrc,
                                              float* __restrict__ enorm) {
    int e = blockIdx.x * blockDim.x + threadIdx.x;
    if (e >= N_EDGES) return;
    int s = src[e], d = dst[e];
    int pos = csrptr[d] + atomicAdd(&cursor[d], 1);
    esrc[pos] = s;
    enorm[pos] = dinv[s] * ew[e] * dinv[d];
}

// ---------------- converts ----------------

template <int K>
__global__ __launch_bounds__(256) void k_convw(const float* __restrict__ W,
                                               unsigned short* __restrict__ BTh,
                                               unsigned short* __restrict__ BTl) {
    int idx = blockIdx.x * 256 + threadIdx.x;
    if (idx >= K * 512) return;
    int k = idx >> 9, n = idx & 511;
    unsigned short h, l;
    split_bf16(W[idx], h, l);
    BTh[(size_t)n * K + k] = h;
    BTl[(size_t)n * K + k] = l;
}

__global__ __launch_bounds__(256) void k_convx(const float* __restrict__ X,
                                               unsigned short* __restrict__ Xb, int n4) {
    int idx = blockIdx.x * 256 + threadIdx.x;
    if (idx >= n4) return;
    float4 v = ((const float4*)X)[idx];
    uint2 p;
    p.x = (unsigned int)f2bf(v.x) | ((unsigned int)f2bf(v.y) << 16);
    p.y = (unsigned int)f2bf(v.z) | ((unsigned int)f2bf(v.w) << 16);
    ((uint2*)Xb)[idx] = p;
}

// ---------------- aggregation: Y = A_norm X (X bf16), out single bf16 ----------------

template <int F>
__global__ __launch_bounds__(256) void k_agg(const unsigned short* __restrict__ X,
                                             const int* __restrict__ csrptr,
                                             const int* __restrict__ esrc,
                                             const float* __restrict__ enorm,
                                             const float* __restrict__ dinv,
                                             unsigned short* __restrict__ Yb) {
    constexpr int C = F / 64;
    constexpr int U = C / 2;
    int wave = (blockIdx.x * blockDim.x + threadIdx.x) >> 6;
    int lane = threadIdx.x & 63;
    if (wave >= N_NODES) return;
    int i = wave;
    float w0 = dinv[i] * dinv[i];
    float acc[C];
    {
        unsigned int u[U];
        const unsigned short* p = &X[(size_t)i * F + lane * C];
        if constexpr (U == 4) *(uint4*)u = *(const uint4*)p;
        else                  *(uint2*)u = *(const uint2*)p;
        #pragma unroll
        for (int j = 0; j < U; ++j) {
            acc[2 * j]     = w0 * bflo(u[j]);
            acc[2 * j + 1] = w0 * bfhi(u[j]);
        }
    }
    int s = csrptr[i], e = csrptr[i + 1];
    for (int j = s; j < e; ++j) {
        int sr = esrc[j];
        float w = enorm[j];
        unsigned int u[U];
        const unsigned short* p = &X[(size_t)sr * F + lane * C];
        if constexpr (U == 4) *(uint4*)u = *(const uint4*)p;
        else                  *(uint2*)u = *(const uint2*)p;
        #pragma unroll
        for (int q = 0; q < U; ++q) {
            acc[2 * q]     += w * bflo(u[q]);
            acc[2 * q + 1] += w * bfhi(u[q]);
        }
    }
    unsigned int pk[U];
    #pragma unroll
    for (int j = 0; j < U; ++j)
        pk[j] = (unsigned int)f2bf(acc[2 * j]) | ((unsigned int)f2bf(acc[2 * j + 1]) << 16);
    size_t base = (size_t)i * F + lane * C;
    if constexpr (U == 4) *(uint4*)&Yb[base] = *(uint4*)pk;
    else                  *(uint2*)&Yb[base] = *(uint2*)pk;
}

// ---------------- LDS-staged 2-term bf16 MFMA GEMM, 256x128 tile ----------------
// C[M,512] = relu(A*(Bh+Bl) + bias); A single bf16 [M][K], B^T hi/lo [512][K].
// 256x128 tile, BK=32, 8 waves as (wm=wid>>1 in 0..3, wn=wid&1 in 0..1),
// wave-tile 64x64. LDS/buffer: A 16KB + B(h+l) 16KB = 32KB, dbuf 64KB ->
// 2 blocks/CU = 16 waves/CU. Staging per wave = 4x global_load_lds(16B):
//   waves 0-3: A rows [wid*64, wid*64+64), g=0..3
//   waves 4-7: B plane p=(wid-4)>>1, col-half h=(wid-4)&1, g=0..3
// LDS (ushorts): A g*2048+row*8 (16KB); B 8192 + p*4096 + g*1024 + col*8.
template <int K, bool DOT>
__global__ __launch_bounds__(512, 4) void k_mgemm(const unsigned short* __restrict__ Ab,
                                                  const unsigned short* __restrict__ BTh,
                                                  const unsigned short* __restrict__ BTl,
                                                  const float* __restrict__ bias,
                                                  unsigned short* __restrict__ Cb,
                                                  const float* __restrict__ Wl,
                                                  float* __restrict__ pd) {
    constexpr int NT = K / 32;
    __shared__ __align__(16) unsigned short smem[2 * 16384];  // 64 KB

    int wgid = blockIdx.x;
    int rowblk = (wgid >> 5) * 8 + (wgid & 7);     // XCD swizzle: col-siblings 8 apart
    if (rowblk >= NRB) return;
    int colblk = (wgid >> 3) & 3;
    int tid = threadIdx.x, lane = tid & 63, wid = tid >> 6;
    int wm = wid >> 1, wn = wid & 1;
    int row0 = rowblk * 256 + wm * 64;
    int col0 = colblk * 128 + wn * 64;
    int l15 = lane & 15, l4 = lane >> 4;

    // staging role per wave
    const unsigned short* gS;      // per-wave global src base (advances 32/step)
    int ldsoff;                    // per-wave LDS chunk base (ushorts, + g*stride)
    int gstride;                   // LDS stride between g-groups
    if (wid < 4) {
        int r = rowblk * 256 + wid * 64 + lane;
        if (r >= N_NODES) r = N_NODES - 1;         // clamped read, store-guarded
        gS = Ab + (size_t)r * K;
        ldsoff = wid * 512 + lane * 8;             // + g*2048
        gstride = 2048;
    } else {
        int p = (wid - 4) >> 1, h = (wid - 4) & 1;
        const unsigned short* mb = p ? BTl : BTh;
        gS = mb + (size_t)(colblk * 128 + h * 64 + lane) * K;
        ldsoff = 8192 + p * 4096 + h * 512 + lane * 8;  // + g*1024
        gstride = 1024;
    }

    f32x4 acc[4][4];
    #pragma unroll
    for (int a = 0; a < 4; ++a)
        #pragma unroll
        for (int b = 0; b < 4; ++b) acc[a][b] = (f32x4){0.f, 0.f, 0.f, 0.f};

    // NOTE: global_load_lds dest = wave-uniform base + lane*16B; ldsoff already
    // includes lane*8 ushorts, and all lanes' values agree on the uniform base.
    auto STAGE = [&](int b) {
        unsigned short* lb = &smem[b * 16384];
        #pragma unroll
        for (int g = 0; g < 4; ++g)
            __builtin_amdgcn_global_load_lds((gas_ptr)(gS + g * 8),
                                             (las_ptr)(lb + ldsoff - lane * 8 + g * gstride + lane * 8),
                                             16, 0, 0);
    };

    STAGE(0);
    __syncthreads();

    for (int t = 0; t < NT; ++t) {
        int cur = t & 1;
        if (t + 1 < NT) {
            gS += 32;
            STAGE(cur ^ 1);
        }
        const unsigned short* sb = &smem[cur * 16384];
        int aoff = l4 * 2048 + (wm * 64 + l15) * 8;
        int boff = l4 * 1024 + (wn * 64 + l15) * 8;
        bf16x8 a[4];
        #pragma unroll
        for (int mf = 0; mf < 4; ++mf) a[mf] = *(const bf16x8*)&sb[aoff + mf * 128];
        #pragma unroll
        for (int nf = 0; nf < 4; ++nf) {
            bf16x8 bh = *(const bf16x8*)&sb[8192 + boff + nf * 128];
            bf16x8 bl = *(const bf16x8*)&sb[12288 + boff + nf * 128];
            #pragma unroll
            for (int mf = 0; mf < 4; ++mf) {
                acc[mf][nf] = __builtin_amdgcn_mfma_f32_16x16x32_bf16(a[mf], bh, acc[mf][nf], 0, 0, 0);
                acc[mf][nf] = __builtin_amdgcn_mfma_f32_16x16x32_bf16(a[mf], bl, acc[mf][nf], 0, 0, 0);
            }
        }
        __syncthreads();   // drains vmcnt (next tile staged) + lgkm (buf consumed)
    }

    if (!DOT) {
        #pragma unroll
        for (int mf = 0; mf < 4; ++mf)
            #pragma unroll
            for (int nf = 0; nf < 4; ++nf) {
                int c = col0 + nf * 16 + l15;
                float bv = bias[c];
                #pragma unroll
                for (int r = 0; r < 4; ++r) {
                    int row = row0 + mf * 16 + l4 * 4 + r;
                    if (row < N_NODES)
                        Cb[(size_t)row * 512 + c] = f2bf(fmaxf(acc[mf][nf][r] + bv, 0.f));
                }
            }
    } else {
        float rowsum[4][4];
        #pragma unroll
        for (int mf = 0; mf < 4; ++mf)
            #pragma unroll
            for (int r = 0; r < 4; ++r) rowsum[mf][r] = 0.f;
        #pragma unroll
        for (int nf = 0; nf < 4; ++nf) {
            int c = col0 + nf * 16 + l15;
            float bv = bias[c];
            float wv = Wl[c];
            #pragma unroll
            for (int mf = 0; mf < 4; ++mf)
                #pragma unroll
                for (int r = 0; r < 4; ++r)
                    rowsum[mf][r] += fmaxf(acc[mf][nf][r] + bv, 0.f) * wv;
        }
        #pragma unroll
        for (int mf = 0; mf < 4; ++mf)
            #pragma unroll
            for (int r = 0; r < 4; ++r) {
                float v = rowsum[mf][r];
                #pragma unroll
                for (int mask = 1; mask <= 8; mask <<= 1) v += __shfl_xor(v, mask);
                if (l15 == 0) {
                    int row = row0 + mf * 16 + l4 * 4 + r;
                    if (row < N_NODES)
                        pd[(size_t)(colblk * 2 + wn) * PDS + row] = v;
                }
            }
    }
}

// ---------------- pool ----------------

__global__ __launch_bounds__(256) void k_gpool(const float* __restrict__ pd,
                                               const int* __restrict__ batch,
                                               const float* __restrict__ bl,
                                               float* __restrict__ out) {
    int g = blockIdx.x;
    int tid = threadIdx.x;
    float s = 0.f;
    int c = 0;
    for (int i = tid; i < N_NODES; i += 256) {
        if (batch[i] == g) {
            float v = 0.f;
            #pragma unroll
            for (int p = 0; p < 8; ++p) v += pd[(size_t)p * PDS + i];
            s += v;
            c += 1;
        }
    }
    __shared__ float ss[4];
    __shared__ int sc[4];
    int lane = tid & 63, wid = tid >> 6;
    #pragma unroll
    for (int off = 32; off > 0; off >>= 1) {
        s += __shfl_down(s, off);
        c += __shfl_down(c, off);
    }
    if (lane == 0) { ss[wid] = s; sc[wid] = c; }
    __syncthreads();
    if (tid == 0) {
        float S = ss[0] + ss[1] + ss[2] + ss[3];
        int C = sc[0] + sc[1] + sc[2] + sc[3];
        out[g] = S / fmaxf((float)C, 1.0f) + bl[0];
    }
}

// ---------------- launch ----------------

extern "C" void kernel_launch(void* const* d_in, const int* in_sizes, int n_in,
                              void* d_out, int out_size, void* d_ws, size_t ws_size,
                              hipStream_t stream) {
    const float* x  = (const float*)d_in[0];
    const int* ei   = (const int*)d_in[1];
    const float* ew = (const float*)d_in[2];
    const int* batch= (const int*)d_in[3];
    const float* W1 = (const float*)d_in[4];
    const float* b1 = (const float*)d_in[5];
    const float* W2 = (const float*)d_in[6];
    const float* b2 = (const float*)d_in[7];
    const float* Wl = (const float*)d_in[8];
    const float* bl = (const float*)d_in[9];
    float* out = (float*)d_out;

    const int* src = ei;
    const int* dst = ei + N_EDGES;

    float* ws = (float*)d_ws;
    float* deg    = ws + OFF_DEG;
    int*   cnt    = (int*)(ws + OFF_CNT);
    int*   cursor = (int*)(ws + OFF_CURSOR);
    float* dinv   = ws + OFF_DINV;
    int*   csrptr = (int*)(ws + OFF_CSRPTR);
    int*   esrc   = (int*)(ws + OFF_ESRC);
    float* enorm  = ws + OFF_ENORM;
    unsigned short* bt1h = (unsigned short*)(ws + OFF_BT1H);
    unsigned short* bt1l = (unsigned short*)(ws + OFF_BT1L);
    unsigned short* bt2h = (unsigned short*)(ws + OFF_BT2H);
    unsigned short* bt2l = (unsigned short*)(ws + OFF_BT2L);
    float* pd     = ws + OFF_PD;
    unsigned short* xb  = (unsigned short*)(ws + OFF_XB);
    unsigned short* a1  = (unsigned short*)(ws + OFF_A);   // [M,256] bf16
    unsigned short* a2  = (unsigned short*)(ws + OFF_A);   // [M,512] bf16 (a1 dead by then)
    unsigned short* h1b = (unsigned short*)(ws + OFF_H1B); // [M,512] bf16

    hipMemsetAsync(ws, 0, (size_t)ZERO_ELEMS * 4, stream);

    int eb = (N_EDGES + 255) / 256;
    int nb = (N_NODES + 255) / 256;
    int wb = (N_NODES * 64 + 255) / 256;

    k_deg_cnt<<<eb, 256, 0, stream>>>(src, dst, ew, deg, cnt);
    k_dinv<<<nb, 256, 0, stream>>>(deg, dinv);
    k_scan<<<1, 1024, 0, stream>>>(cnt, csrptr, N_NODES);
    k_fill<<<eb, 256, 0, stream>>>(src, dst, ew, dinv, csrptr, cursor, esrc, enorm);

    k_convw<IN_CH><<<(IN_CH * 512 + 255) / 256, 256, 0, stream>>>(W1, bt1h, bt1l);
    k_convw<HID><<<(HID * 512 + 255) / 256, 256, 0, stream>>>(W2, bt2h, bt2l);
    k_convx<<<(N_NODES * IN_CH / 4 + 255) / 256, 256, 0, stream>>>(x, xb, N_NODES * IN_CH / 4);

    // layer 1
    k_agg<IN_CH><<<wb, 256, 0, stream>>>(xb, csrptr, esrc, enorm, dinv, a1);
    k_mgemm<IN_CH, false><<<MG_GRID, 512, 0, stream>>>(a1, bt1h, bt1l, b1, h1b, nullptr, nullptr);

    // layer 2 (+ fused dot with Wl)
    k_agg<HID><<<wb, 256, 0, stream>>>(h1b, csrptr, esrc, enorm, dinv, a2);
    k_mgemm<HID, true><<<MG_GRID, 512, 0, stream>>>(a2, bt2h, bt2l, b2, nullptr, Wl, pd);

    // pool + head
    k_gpool<<<N_GRAPHS, 256, 0, stream>>>(pd, batch, bl, out);
}

// Round 13
// 681.610 us; speedup vs baseline: 2.3011x; 1.0520x over previous
//
#include <hip/hip_runtime.h>
#include <hip/hip_bf16.h>

// ---------------------------------------------------------------------------
// GNNRegression: 2-layer GCN + global mean pool + linear head. MI355X gfx950.
// R3: atomic-free pool (1568->1245us).    R4: split-bf16 MFMA GEMM (->1066us).
// R5: bf16 gather + XCD swizzle (->937us).
// R6/R9: LDS-staged 2-term GEMM, A single-bf16 (->779us).
// R11: 256x128 tile, 8 waves, 16 waves/CU (->717us, mgemm out of top-5).
// R12: k_agg<512> top (125us): 1-deep pointer-chase gather -> MLP starvation
//      (FETCH 402MB, HBM-path 3.2 of 6.3 TB/s, VALU 23%, occ 71% -- nothing
//      saturated). Unroll neighbor loop x4 with prefetched indices: 4
//      independent row loads in flight per lane.
// ---------------------------------------------------------------------------

#define N_NODES 50000
#define N_EDGES 800000
#define IN_CH   256
#define HID     512
#define N_GRAPHS 64
#define PDS     50048   // pd row stride
#define NRB     196     // row blocks of 256
#define MG_GRID 800     // ceil(196/8)*8=200 rowblk-slots * 4 colblks

typedef short bf16x8 __attribute__((ext_vector_type(8)));
typedef float f32x4  __attribute__((ext_vector_type(4)));

typedef const __attribute__((address_space(1))) void* gas_ptr;
typedef __attribute__((address_space(3))) void* las_ptr;

// ---------------- workspace layout (4-byte slots) ----------------
#define OFF_DEG    128
#define OFF_CNT    (OFF_DEG + N_NODES)
#define OFF_CURSOR (OFF_CNT + N_NODES)
#define ZERO_ELEMS (OFF_CURSOR + N_NODES)            // 150128
#define OFF_DINV   ZERO_ELEMS
#define OFF_CSRPTR (OFF_DINV + N_NODES)
#define OFF_ESRC   (OFF_CSRPTR + N_NODES + 1)
#define OFF_ENORM  (OFF_ESRC + N_EDGES)
#define OFF_BT1H   1850368                           // 256*512 bf16 = 65536 slots
#define OFF_BT1L   (OFF_BT1H + 65536)
#define OFF_BT2H   (OFF_BT1L + 65536)                // 512*512 bf16 = 131072 slots
#define OFF_BT2L   (OFF_BT2H + 131072)
#define OFF_PD     (OFF_BT2L + 131072)               // 8*PDS floats
#define OFF_XB     2643968                           // x bf16 [M,256]: 6.4M slots
#define OFF_A      (OFF_XB + 6400000)                // A1 [M,256] / A2 [M,512] (12.8M slots)
#define OFF_H1B    (OFF_A + 12800000)                // h1 bf16 [M,512]: 12.8M slots

// ---------------- helpers ----------------

static __device__ inline unsigned short f2bf(float f) {   // RTN-even
    unsigned int u = __float_as_uint(f);
    return (unsigned short)((u + 0x7fff + ((u >> 16) & 1)) >> 16);
}
static __device__ inline float bf2f(unsigned short b) {
    return __uint_as_float(((unsigned int)b) << 16);
}
static __device__ inline void split_bf16(float v, unsigned short& hi, unsigned short& lo) {
    hi = f2bf(v);
    lo = f2bf(v - bf2f(hi));
}
static __device__ inline float bflo(unsigned int u) { return __uint_as_float(u << 16); }
static __device__ inline float bfhi(unsigned int u) { return __uint_as_float(u & 0xFFFF0000u); }

// ---------------- CSR build ----------------

__global__ __launch_bounds__(256) void k_deg_cnt(const int* __restrict__ src,
                                                 const int* __restrict__ dst,
                                                 const float* __restrict__ ew,
                                                 float* __restrict__ deg,
                                                 int* __restrict__ cnt) {
    int e = blockIdx.x * blockDim.x + threadIdx.x;
    if (e >= N_EDGES) return;
    int d = dst[e];
    atomicAdd(&deg[d], ew[e]);
    atomicAdd(&cnt[d], 1);
}

__global__ __launch_bounds__(256) void k_dinv(const float* __restrict__ deg,
                                              float* __restrict__ dinv) {
    int i = blockIdx.x * blockDim.x + threadIdx.x;
    if (i >= N_NODES) return;
    dinv[i] = 1.0f / sqrtf(deg[i] + 1.0f);
}

__global__ __launch_bounds__(1024) void k_scan(const int* __restrict__ cnt,
                                               int* __restrict__ ptr, int n) {
    __shared__ int wsum[16];
    __shared__ int carry;
    int tid = threadIdx.x, lane = tid & 63, wid = tid >> 6;
    if (tid == 0) carry = 0;
    __syncthreads();
    for (int base = 0; base < n; base += 1024) {
        int i = base + tid;
        int v = (i < n) ? cnt[i] : 0;
        int incl = v;
        #pragma unroll
        for (int off = 1; off < 64; off <<= 1) {
            int t = __shfl_up(incl, off);
            if (lane >= off) incl += t;
        }
        if (lane == 63) wsum[wid] = incl;
        __syncthreads();
        if (tid == 0) {
            int run = carry;
            #pragma unroll
            for (int k = 0; k < 16; ++k) { int t = wsum[k]; wsum[k] = run; run += t; }
            carry = run;
        }
        __syncthreads();
        if (i < n) ptr[i] = wsum[wid] + incl - v;
        __syncthreads();
    }
    if (threadIdx.x == 0) ptr[n] = carry;
}

__global__ __launch_bounds__(256) void k_fill(const int* __restrict__ src,
                                              const int* __restrict__ dst,
                                              const float* __restrict__ ew,
                                              const float* __restrict__ dinv,
                                              const int* __restrict__ csrptr,
                                              int* __restrict__ cursor,
                                              int* __restrict__ esrc,
                                              float* __restrict__ enorm) {
    int e = blockIdx.x * blockDim.x + threadIdx.x;
    if (e >= N_EDGES) return;
    int s = src[e], d = dst[e];
    int pos = csrptr[d] + atomicAdd(&cursor[d], 1);
    esrc[pos] = s;
    enorm[pos] = dinv[s] * ew[e] * dinv[d];
}

// ---------------- converts ----------------

template <int K>
__global__ __launch_bounds__(256) void k_convw(const float* __restrict__ W,
                                               unsigned short* __restrict__ BTh,
                                               unsigned short* __restrict__ BTl) {
    int idx = blockIdx.x * 256 + threadIdx.x;
    if (idx >= K * 512) return;
    int k = idx >> 9, n = idx & 511;
    unsigned short h, l;
    split_bf16(W[idx], h, l);
    BTh[(size_t)n * K + k] = h;
    BTl[(size_t)n * K + k] = l;
}

__global__ __launch_bounds__(256) void k_convx(const float* __restrict__ X,
                                               unsigned short* __restrict__ Xb, int n4) {
    int idx = blockIdx.x * 256 + threadIdx.x;
    if (idx >= n4) return;
    float4 v = ((const float4*)X)[idx];
    uint2 p;
    p.x = (unsigned int)f2bf(v.x) | ((unsigned int)f2bf(v.y) << 16);
    p.y = (unsigned int)f2bf(v.z) | ((unsigned int)f2bf(v.w) << 16);
    ((uint2*)Xb)[idx] = p;
}

// ---------------- aggregation: Y = A_norm X (X bf16), out single bf16 ----------------
// R12: neighbor loop unrolled x4 with prefetched indices -> 4 independent
// row loads in flight per lane (MLP 1 -> 4).

template <int F>
__global__ __launch_bounds__(256) void k_agg(const unsigned short* __restrict__ X,
                                             const int* __restrict__ csrptr,
                                             const int* __restrict__ esrc,
                                             const float* __restrict__ enorm,
                                             const float* __restrict__ dinv,
                                             unsigned short* __restrict__ Yb) {
    constexpr int C = F / 64;
    constexpr int U = C / 2;
    int wave = (blockIdx.x * blockDim.x + threadIdx.x) >> 6;
    int lane = threadIdx.x & 63;
    if (wave >= N_NODES) return;
    int i = wave;
    float w0 = dinv[i] * dinv[i];
    float acc[C];
    {
        unsigned int u[U];
        const unsigned short* p = &X[(size_t)i * F + lane * C];
        if constexpr (U == 4) *(uint4*)u = *(const uint4*)p;
        else                  *(uint2*)u = *(const uint2*)p;
        #pragma unroll
        for (int j = 0; j < U; ++j) {
            acc[2 * j]     = w0 * bflo(u[j]);
            acc[2 * j + 1] = w0 * bfhi(u[j]);
        }
    }
    int s = csrptr[i], e = csrptr[i + 1];
    int j = s;
    for (; j + 4 <= e; j += 4) {
        int sr0 = esrc[j], sr1 = esrc[j + 1], sr2 = esrc[j + 2], sr3 = esrc[j + 3];
        float we0 = enorm[j], we1 = enorm[j + 1], we2 = enorm[j + 2], we3 = enorm[j + 3];
        unsigned int u0[U], u1[U], u2[U], u3[U];
        const unsigned short* p0 = &X[(size_t)sr0 * F + lane * C];
        const unsigned short* p1 = &X[(size_t)sr1 * F + lane * C];
        const unsigned short* p2 = &X[(size_t)sr2 * F + lane * C];
        const unsigned short* p3 = &X[(size_t)sr3 * F + lane * C];
        if constexpr (U == 4) {
            *(uint4*)u0 = *(const uint4*)p0;
            *(uint4*)u1 = *(const uint4*)p1;
            *(uint4*)u2 = *(const uint4*)p2;
            *(uint4*)u3 = *(const uint4*)p3;
        } else {
            *(uint2*)u0 = *(const uint2*)p0;
            *(uint2*)u1 = *(const uint2*)p1;
            *(uint2*)u2 = *(const uint2*)p2;
            *(uint2*)u3 = *(const uint2*)p3;
        }
        #pragma unroll
        for (int q = 0; q < U; ++q) {
            acc[2 * q]     += we0 * bflo(u0[q]) + we1 * bflo(u1[q]) + we2 * bflo(u2[q]) + we3 * bflo(u3[q]);
            acc[2 * q + 1] += we0 * bfhi(u0[q]) + we1 * bfhi(u1[q]) + we2 * bfhi(u2[q]) + we3 * bfhi(u3[q]);
        }
    }
    for (; j < e; ++j) {
        int sr = esrc[j];
        float w = enorm[j];
        unsigned int u[U];
        const unsigned short* p = &X[(size_t)sr * F + lane * C];
        if constexpr (U == 4) *(uint4*)u = *(const uint4*)p;
        else                  *(uint2*)u = *(const uint2*)p;
        #pragma unroll
        for (int q = 0; q < U; ++q) {
            acc[2 * q]     += w * bflo(u[q]);
            acc[2 * q + 1] += w * bfhi(u[q]);
        }
    }
    unsigned int pk[U];
    #pragma unroll
    for (int q = 0; q < U; ++q)
        pk[q] = (unsigned int)f2bf(acc[2 * q]) | ((unsigned int)f2bf(acc[2 * q + 1]) << 16);
    size_t base = (size_t)i * F + lane * C;
    if constexpr (U == 4) *(uint4*)&Yb[base] = *(uint4*)pk;
    else                  *(uint2*)&Yb[base] = *(uint2*)pk;
}

// ---------------- LDS-staged 2-term bf16 MFMA GEMM, 256x128 tile ----------------
// (unchanged from R11 -- verified at 717us total)
template <int K, bool DOT>
__global__ __launch_bounds__(512, 4) void k_mgemm(const unsigned short* __restrict__ Ab,
                                                  const unsigned short* __restrict__ BTh,
                                                  const unsigned short* __restrict__ BTl,
                                                  const float* __restrict__ bias,
                                                  unsigned short* __restrict__ Cb,
                                                  const float* __restrict__ Wl,
                                                  float* __restrict__ pd) {
    constexpr int NT = K / 32;
    __shared__ __align__(16) unsigned short smem[2 * 16384];  // 64 KB

    int wgid = blockIdx.x;
    int rowblk = (wgid >> 5) * 8 + (wgid & 7);     // XCD swizzle: col-siblings 8 apart
    if (rowblk >= NRB) return;
    int colblk = (wgid >> 3) & 3;
    int tid = threadIdx.x, lane = tid & 63, wid = tid >> 6;
    int wm = wid >> 1, wn = wid & 1;
    int row0 = rowblk * 256 + wm * 64;
    int col0 = colblk * 128 + wn * 64;
    int l15 = lane & 15, l4 = lane >> 4;

    // staging role per wave
    const unsigned short* gS;      // per-wave global src base (advances 32/step)
    int ldsoff;                    // per-wave LDS chunk base (ushorts, + g*stride)
    int gstride;                   // LDS stride between g-groups
    if (wid < 4) {
        int r = rowblk * 256 + wid * 64 + lane;
        if (r >= N_NODES) r = N_NODES - 1;         // clamped read, store-guarded
        gS = Ab + (size_t)r * K;
        ldsoff = wid * 512;                        // + g*2048 (+ lane*16B by HW)
        gstride = 2048;
    } else {
        int p = (wid - 4) >> 1, h = (wid - 4) & 1;
        const unsigned short* mb = p ? BTl : BTh;
        gS = mb + (size_t)(colblk * 128 + h * 64 + lane) * K;
        ldsoff = 8192 + p * 4096 + h * 512;        // + g*1024
        gstride = 1024;
    }

    f32x4 acc[4][4];
    #pragma unroll
    for (int a = 0; a < 4; ++a)
        #pragma unroll
        for (int b = 0; b < 4; ++b) acc[a][b] = (f32x4){0.f, 0.f, 0.f, 0.f};

    auto STAGE = [&](int b) {
        unsigned short* lb = &smem[b * 16384];
        #pragma unroll
        for (int g = 0; g < 4; ++g)
            __builtin_amdgcn_global_load_lds((gas_ptr)(gS + g * 8),
                                             (las_ptr)(lb + ldsoff + g * gstride),
                                             16, 0, 0);
    };

    STAGE(0);
    __syncthreads();

    for (int t = 0; t < NT; ++t) {
        int cur = t & 1;
        if (t + 1 < NT) {
            gS += 32;
            STAGE(cur ^ 1);
        }
        const unsigned short* sb = &smem[cur * 16384];
        int aoff = l4 * 2048 + (wm * 64 + l15) * 8;
        int boff = l4 * 1024 + (wn * 64 + l15) * 8;
        bf16x8 a[4];
        #pragma unroll
        for (int mf = 0; mf < 4; ++mf) a[mf] = *(const bf16x8*)&sb[aoff + mf * 128];
        #pragma unroll
        for (int nf = 0; nf < 4; ++nf) {
            bf16x8 bh = *(const bf16x8*)&sb[8192 + boff + nf * 128];
            bf16x8 bl = *(const bf16x8*)&sb[12288 + boff + nf * 128];
            #pragma unroll
            for (int mf = 0; mf < 4; ++mf) {
                acc[mf][nf] = __builtin_amdgcn_mfma_f32_16x16x32_bf16(a[mf], bh, acc[mf][nf], 0, 0, 0);
                acc[mf][nf] = __builtin_amdgcn_mfma_f32_16x16x32_bf16(a[mf], bl, acc[mf][nf], 0, 0, 0);
            }
        }
        __syncthreads();   // drains vmcnt (next tile staged) + lgkm (buf consumed)
    }

    if (!DOT) {
        #pragma unroll
        for (int mf = 0; mf < 4; ++mf)
            #pragma unroll
            for (int nf = 0; nf < 4; ++nf) {
                int c = col0 + nf * 16 + l15;
                float bv = bias[c];
                #pragma unroll
                for (int r = 0; r < 4; ++r) {
                    int row = row0 + mf * 16 + l4 * 4 + r;
                    if (row < N_NODES)
                        Cb[(size_t)row * 512 + c] = f2bf(fmaxf(acc[mf][nf][r] + bv, 0.f));
                }
            }
    } else {
        float rowsum[4][4];
        #pragma unroll
        for (int mf = 0; mf < 4; ++mf)
            #pragma unroll
            for (int r = 0; r < 4; ++r) rowsum[mf][r] = 0.f;
        #pragma unroll
        for (int nf = 0; nf < 4; ++nf) {
            int c = col0 + nf * 16 + l15;
            float bv = bias[c];
            float wv = Wl[c];
            #pragma unroll
            for (int mf = 0; mf < 4; ++mf)
                #pragma unroll
                for (int r = 0; r < 4; ++r)
                    rowsum[mf][r] += fmaxf(acc[mf][nf][r] + bv, 0.f) * wv;
        }
        #pragma unroll
        for (int mf = 0; mf < 4; ++mf)
            #pragma unroll
            for (int r = 0; r < 4; ++r) {
                float v = rowsum[mf][r];
                #pragma unroll
                for (int mask = 1; mask <= 8; mask <<= 1) v += __shfl_xor(v, mask);
                if (l15 == 0) {
                    int row = row0 + mf * 16 + l4 * 4 + r;
                    if (row < N_NODES)
                        pd[(size_t)(colblk * 2 + wn) * PDS + row] = v;
                }
            }
    }
}

// ---------------- pool ----------------

__global__ __launch_bounds__(256) void k_gpool(const float* __restrict__ pd,
                                               const int* __restrict__ batch,
                                               const float* __restrict__ bl,
                                               float* __restrict__ out) {
    int g = blockIdx.x;
    int tid = threadIdx.x;
    float s = 0.f;
    int c = 0;
    for (int i = tid; i < N_NODES; i += 256) {
        if (batch[i] == g) {
            float v = 0.f;
            #pragma unroll
            for (int p = 0; p < 8; ++p) v += pd[(size_t)p * PDS + i];
            s += v;
            c += 1;
        }
    }
    __shared__ float ss[4];
    __shared__ int sc[4];
    int lane = tid & 63, wid = tid >> 6;
    #pragma unroll
    for (int off = 32; off > 0; off >>= 1) {
        s += __shfl_down(s, off);
        c += __shfl_down(c, off);
    }
    if (lane == 0) { ss[wid] = s; sc[wid] = c; }
    __syncthreads();
    if (tid == 0) {
        float S = ss[0] + ss[1] + ss[2] + ss[3];
        int C = sc[0] + sc[1] + sc[2] + sc[3];
        out[g] = S / fmaxf((float)C, 1.0f) + bl[0];
    }
}

// ---------------- launch ----------------

extern "C" void kernel_launch(void* const* d_in, const int* in_sizes, int n_in,
                              void* d_out, int out_size, void* d_ws, size_t ws_size,
                              hipStream_t stream) {
    const float* x  = (const float*)d_in[0];
    const int* ei   = (const int*)d_in[1];
    const float* ew = (const float*)d_in[2];
    const int* batch= (const int*)d_in[3];
    const float* W1 = (const float*)d_in[4];
    const float* b1 = (const float*)d_in[5];
    const float* W2 = (const float*)d_in[6];
    const float* b2 = (const float*)d_in[7];
    const float* Wl = (const float*)d_in[8];
    const float* bl = (const float*)d_in[9];
    float* out = (float*)d_out;

    const int* src = ei;
    const int* dst = ei + N_EDGES;

    float* ws = (float*)d_ws;
    float* deg    = ws + OFF_DEG;
    int*   cnt    = (int*)(ws + OFF_CNT);
    int*   cursor = (int*)(ws + OFF_CURSOR);
    float* dinv   = ws + OFF_DINV;
    int*   csrptr = (int*)(ws + OFF_CSRPTR);
    int*   esrc   = (int*)(ws + OFF_ESRC);
    float* enorm  = ws + OFF_ENORM;
    unsigned short* bt1h = (unsigned short*)(ws + OFF_BT1H);
    unsigned short* bt1l = (unsigned short*)(ws + OFF_BT1L);
    unsigned short* bt2h = (unsigned short*)(ws + OFF_BT2H);
    unsigned short* bt2l = (unsigned short*)(ws + OFF_BT2L);
    float* pd     = ws + OFF_PD;
    unsigned short* xb  = (unsigned short*)(ws + OFF_XB);
    unsigned short* a1  = (unsigned short*)(ws + OFF_A);   // [M,256] bf16
    unsigned short* a2  = (unsigned short*)(ws + OFF_A);   // [M,512] bf16 (a1 dead by then)
    unsigned short* h1b = (unsigned short*)(ws + OFF_H1B); // [M,512] bf16

    hipMemsetAsync(ws, 0, (size_t)ZERO_ELEMS * 4, stream);

    int eb = (N_EDGES + 255) / 256;
    int nb = (N_NODES + 255) / 256;
    int wb = (N_NODES * 64 + 255) / 256;

    k_deg_cnt<<<eb, 256, 0, stream>>>(src, dst, ew, deg, cnt);
    k_dinv<<<nb, 256, 0, stream>>>(deg, dinv);
    k_scan<<<1, 1024, 0, stream>>>(cnt, csrptr, N_NODES);
    k_fill<<<eb, 256, 0, stream>>>(src, dst, ew, dinv, csrptr, cursor, esrc, enorm);

    k_convw<IN_CH><<<(IN_CH * 512 + 255) / 256, 256, 0, stream>>>(W1, bt1h, bt1l);
    k_convw<HID><<<(HID * 512 + 255) / 256, 256, 0, stream>>>(W2, bt2h, bt2l);
    k_convx<<<(N_NODES * IN_CH / 4 + 255) / 256, 256, 0, stream>>>(x, xb, N_NODES * IN_CH / 4);

    // layer 1
    k_agg<IN_CH><<<wb, 256, 0, stream>>>(xb, csrptr, esrc, enorm, dinv, a1);
    k_mgemm<IN_CH, false><<<MG_GRID, 512, 0, stream>>>(a1, bt1h, bt1l, b1, h1b, nullptr, nullptr);

    // layer 2 (+ fused dot with Wl)
    k_agg<HID><<<wb, 256, 0, stream>>>(h1b, csrptr, esrc, enorm, dinv, a2);
    k_mgemm<HID, true><<<MG_GRID, 512, 0, stream>>>(a2, bt2h, bt2l, b2, nullptr, Wl, pd);

    // pool + head
    k_gpool<<<N_GRAPHS, 256, 0, stream>>>(pd, batch, bl, out);
}